// Round 4
// baseline (2497.186 us; speedup 1.0000x reference)
//
#include <hip/hip_runtime.h>
#include <hip/hip_bf16.h>
#include <math.h>

#define Bb 2
#define Ss 16
#define Nn 5000
#define Hh 64
#define Ee 20000
#define BSn (Bb*Ss)          // 32
#define ROWS (BSn*Nn)        // 160000
#define XN 10240000          // B*S*N*H elements

typedef __hip_bfloat16 bf16;

__device__ __forceinline__ float bf2f(bf16 v){ return __bfloat162float(v); }
__device__ __forceinline__ bf16 f2bf(float v){ return __float2bfloat16(v); }
__device__ __forceinline__ float gelu_f(float x){
  return 0.5f*x*(1.0f + erff(x*0.70710678118654752f));
}
__device__ __forceinline__ int sniff_f32(const void* tng){
  // tn_g is all-ones. fp32 1.0 little-endian -> first u16 = 0x0000; bf16 1.0 -> 0x3F80
  return (((const unsigned short*)tng)[0] == 0) ? 1 : 0;
}
__device__ __forceinline__ float rl(float v, int l){
  return __uint_as_float(__builtin_amdgcn_readlane(__float_as_uint(v), l));
}

// packed-weight element offsets (order = d_in[2..28])
#define W_EA   0
#define W_INW  20000
#define W_INB  32288
#define W_OW   32480
#define W_OB   36576
#define W_TNG  36640
#define W_TNB  36704
#define W_EW1  36768
#define W_EB1  36832
#define W_EW2  36896
#define W_EB2  40992
#define W_MW1  41056
#define W_MB1  65632
#define W_MW2  65760
#define W_MB2  73952
#define W_UW1  74016
#define W_UB1  82208
#define W_UW2  82272
#define W_UB2  86368
#define W_SNG  86432
#define W_SNB  86496
#define W_FW1  86560
#define W_FB1  102944
#define W_FW2  103200
#define W_FB2  119584
#define W_FNG  119648
#define W_FNB  119712
#define W_TOT  119776

// ---------------- normalize x -> bf16 ---------------------------------------
__global__ __launch_bounds__(256) void k_norm_x(const void* __restrict__ x,
                                                const void* __restrict__ tng,
                                                bf16* __restrict__ xn){
  int f32 = sniff_f32(tng);
  size_t i = (size_t)blockIdx.x*256 + threadIdx.x;   // grid covers XN exactly
  if (f32) xn[i] = f2bf(((const float*)x)[i]);
  else     xn[i] = ((const bf16*)x)[i];
}

// ---------------- normalize all weights -> packed bf16 ----------------------
struct WPtrs { const void* p[27]; };
__global__ __launch_bounds__(256) void k_norm_w(WPtrs wp_in, const void* __restrict__ tng,
                                                bf16* __restrict__ out){
  const int wseg[27] = {20000,12288,192,4096,64,64,64,64,64,4096,64,24576,128,8192,64,
                        8192,64,4096,64,64,64,16384,256,16384,64,64,64};
  int f32 = sniff_f32(tng);
  int i = blockIdx.x*256 + threadIdx.x;
  if (i >= W_TOT) return;
  int seg = 0, off = i;
  while (off >= wseg[seg]) { off -= wseg[seg]; ++seg; }
  const void* p = wp_in.p[seg];
  out[i] = f32 ? f2bf(((const float*)p)[off]) : ((const bf16*)p)[off];
}

// ---------------- Stage 1: temporal attention + LN, one block per (b,n) ----
__global__ __launch_bounds__(256) void k_attn(
    const bf16* __restrict__ xn, const bf16* __restrict__ wp, bf16* __restrict__ buf1)
{
  __shared__ float xt[16][64];
  __shared__ float qq[16][64];
  __shared__ float kk[16][64];
  __shared__ float vsm[16][64];
  __shared__ float ao[16][64];
  __shared__ float mu[16], rs[16];
  int t = threadIdx.x;
  int b = blockIdx.x / Nn, n = blockIdx.x - b*Nn;
  for (int i = t; i < 16*64; i += 256) {
    int s = i >> 6, h = i & 63;
    xt[s][h] = bf2f(xn[(((size_t)(b*Ss+s))*Nn + n)*64 + h]);
  }
  __syncthreads();
  for (int i = t; i < 16*192; i += 256) {
    int s = i / 192, j = i - s*192;
    float acc = bf2f(wp[W_INB + j]);
    for (int h = 0; h < 64; ++h) acc += xt[s][h]*bf2f(wp[W_INW + h*192 + j]);
    if (j < 64) qq[s][j] = acc;
    else if (j < 128) kk[s][j-64] = acc;
    else vsm[s][j-128] = acc;
  }
  __syncthreads();
  if (t < 64) {
    int hd = t >> 4, sq = t & 15;
    float sc[16]; float mx = -3.0e38f;
    #pragma unroll
    for (int sk = 0; sk < 16; ++sk) {
      float a = 0.f;
      #pragma unroll
      for (int d = 0; d < 16; ++d) a += qq[sq][hd*16+d]*kk[sk][hd*16+d];
      a *= 0.25f;
      sc[sk] = a; mx = fmaxf(mx, a);
    }
    float ssum = 0.f;
    #pragma unroll
    for (int sk = 0; sk < 16; ++sk) { sc[sk] = expf(sc[sk]-mx); ssum += sc[sk]; }
    float inv = 1.0f/ssum;
    #pragma unroll
    for (int d = 0; d < 16; ++d) {
      float a = 0.f;
      #pragma unroll
      for (int sk = 0; sk < 16; ++sk) a += sc[sk]*vsm[sk][hd*16+d];
      ao[sq][hd*16+d] = a*inv;
    }
  }
  __syncthreads();
  for (int i = t; i < 16*64; i += 256) {
    int s = i >> 6, j = i & 63;
    float acc = bf2f(wp[W_OB + j]);
    for (int h = 0; h < 64; ++h) acc += ao[s][h]*bf2f(wp[W_OW + h*64 + j]);
    qq[s][j] = xt[s][j] + acc;
  }
  __syncthreads();
  if (t < 16) {
    float m = 0.f;
    for (int h = 0; h < 64; ++h) m += qq[t][h];
    m *= (1.0f/64.0f);
    float v2 = 0.f;
    for (int h = 0; h < 64; ++h) { float d = qq[t][h]-m; v2 += d*d; }
    mu[t] = m; rs[t] = rsqrtf(v2*(1.0f/64.0f) + 1e-5f);
  }
  __syncthreads();
  for (int i = t; i < 16*64; i += 256) {
    int s = i >> 6, j = i & 63;
    float o = (qq[s][j]-mu[s])*rs[s]*bf2f(wp[W_TNG + j]) + bf2f(wp[W_TNB + j]);
    buf1[(((size_t)(b*Ss+s))*Nn + n)*64 + j] = f2bf(o);
  }
}

// ---------------- Stage 2a: edge embedding -> c_e = m_b1 + edge_emb @ Wc ----
__global__ __launch_bounds__(128) void k_edge(
    const bf16* __restrict__ wp, bf16* __restrict__ c_e)
{
  int e = blockIdx.x;
  __shared__ float tmp[64], emb[64];
  int t = threadIdx.x;
  float a = bf2f(wp[W_EA + e]);
  if (t < 64) tmp[t] = gelu_f(a*bf2f(wp[W_EW1 + t]) + bf2f(wp[W_EB1 + t]));
  __syncthreads();
  if (t < 64) {
    float acc = bf2f(wp[W_EB2 + t]);
    for (int h = 0; h < 64; ++h) acc += tmp[h]*bf2f(wp[W_EW2 + h*64 + t]);
    emb[t] = acc;
  }
  __syncthreads();
  float acc = bf2f(wp[W_MB1 + t]);
  for (int h = 0; h < 64; ++h) acc += emb[h]*bf2f(wp[W_MW1 + (128+h)*128 + t]);
  c_e[(size_t)e*128 + t] = f2bf(acc);
}

// ---------------- CSR build ------------------------------------------------
__global__ void k_deg(const int* __restrict__ ei, int* __restrict__ deg){
  int e = blockIdx.x*256 + threadIdx.x;
  if (e < Ee) atomicAdd(&deg[ei[Ee + e]], 1);
}

__global__ __launch_bounds__(256) void k_scan(const int* __restrict__ deg, int* __restrict__ row_st){
  __shared__ int part[256];
  int t = threadIdx.x;
  int base = t*20;
  int s = 0;
  for (int i = 0; i < 20; ++i) { int idx = base+i; if (idx < Nn) s += deg[idx]; }
  part[t] = s;
  __syncthreads();
  for (int off = 1; off < 256; off <<= 1) {
    int v = (t >= off) ? part[t-off] : 0;
    __syncthreads();
    part[t] += v;
    __syncthreads();
  }
  int run = (t == 0) ? 0 : part[t-1];
  for (int i = 0; i < 20; ++i) {
    int idx = base + i;
    if (idx < Nn) { row_st[idx] = run; run += deg[idx]; }
    else if (idx == Nn) { row_st[Nn] = run; }
  }
}

__global__ void k_fill(const int* __restrict__ ei, const int* __restrict__ row_st,
                       int* __restrict__ cursor, int* __restrict__ sorted){
  int e = blockIdx.x*256 + threadIdx.x;
  if (e >= Ee) return;
  int d = ei[Ee + e];
  int pos = atomicAdd(&cursor[d], 1);
  sorted[row_st[d] + pos] = e;
}

// ---------------- Stage 2c: per-edge msg (on-the-fly P), aggr, update, LN ---
// one wave per segment (bs,n); 4 segments per block.
// READS buf1 (stage-1 out, including gathers of other rows) and WRITES buf2 —
// no in-place update: cross-block gather of buf1[src] must never see stage-2
// output (this race was R3's 1.47 absmax bug).
__global__ __launch_bounds__(256) void k_msg_upd(
    const int* __restrict__ ei, const int* __restrict__ row_st, const int* __restrict__ sorted,
    const bf16* __restrict__ c_e, const bf16* __restrict__ wp,
    const bf16* __restrict__ buf1, bf16* __restrict__ buf2)
{
  __shared__ bf16 wbl[64][128];   // 16KB: Wb = m_w1 rows 64..127 (for Q)
  __shared__ float hsum[4][128];
  __shared__ float upd[4][128];
  int t = threadIdx.x;
  int w = t >> 6, lane = t & 63;
  for (int i = t; i < 64*128; i += 256)
    wbl[i>>7][i&127] = wp[W_MW1 + (64 + (i>>7))*128 + (i&127)];
  // register-cache Wa-Wb columns `lane` and `lane+64`
  float wc0[64], wc1[64];
  #pragma unroll
  for (int h = 0; h < 64; ++h) {
    wc0[h] = bf2f(wp[W_MW1 + h*128 + lane])    - bf2f(wp[W_MW1 + (64+h)*128 + lane]);
    wc1[h] = bf2f(wp[W_MW1 + h*128 + 64+lane]) - bf2f(wp[W_MW1 + (64+h)*128 + 64+lane]);
  }
  int sid = blockIdx.x*4 + w;
  int bs = sid / Nn, n = sid - bs*Nn;
  size_t rowoff = (size_t)(bs*Nn + n);
  float xi = bf2f(buf1[rowoff*64 + lane]);
  __syncthreads();
  // Q for cols lane, lane+64 (x_i broadcast via readlane, Wb from LDS)
  float q0 = 0.f, q1 = 0.f;
  #pragma unroll
  for (int h = 0; h < 64; ++h) {
    float xv = rl(xi, h);
    q0 += xv*bf2f(wbl[h][lane]);
    q1 += xv*bf2f(wbl[h][64+lane]);
  }
  const bf16* xb = buf1 + (size_t)bs*Nn*64;
  int s0 = row_st[n], s1 = row_st[n+1];
  float a0 = 0.f, a1 = 0.f;
  for (int ii = s0; ii < s1; ++ii) {
    int e = sorted[ii];
    int src = ei[e];
    float xj = bf2f(xb[(size_t)src*64 + lane]);
    float p0 = 0.f, p1 = 0.f;
    #pragma unroll
    for (int h = 0; h < 64; ++h) {
      float xv = rl(xj, h);
      p0 += xv*wc0[h];
      p1 += xv*wc1[h];
    }
    a0 += gelu_f(p0 + q0 + bf2f(c_e[(size_t)e*128 + lane]));
    a1 += gelu_f(p1 + q1 + bf2f(c_e[(size_t)e*128 + 64+lane]));
  }
  hsum[w][lane]    = a0;
  hsum[w][64+lane] = a1;
  __syncthreads();
  float deg_f = (float)(s1 - s0);
  float aggr = deg_f * bf2f(wp[W_MB2 + lane]);
  for (int k = 0; k < 128; ++k) aggr += hsum[w][k]*bf2f(wp[W_MW2 + k*64 + lane]);
  upd[w][lane]    = xi;
  upd[w][64+lane] = aggr;
  __syncthreads();
  float hu = bf2f(wp[W_UB1 + lane]);
  for (int i = 0; i < 128; ++i) hu += upd[w][i]*bf2f(wp[W_UW1 + i*64 + lane]);
  hu = gelu_f(hu);
  __syncthreads();
  hsum[w][lane] = hu;
  __syncthreads();
  float sp = bf2f(wp[W_UB2 + lane]);
  for (int k = 0; k < 64; ++k) sp += hsum[w][k]*bf2f(wp[W_UW2 + k*64 + lane]);
  float resid = xi + sp;
  float m = resid;
  for (int off = 32; off > 0; off >>= 1) m += __shfl_xor(m, off, 64);
  m *= (1.0f/64.0f);
  float d = resid - m;
  float vv = d*d;
  for (int off = 32; off > 0; off >>= 1) vv += __shfl_xor(vv, off, 64);
  vv *= (1.0f/64.0f);
  float o = d * rsqrtf(vv + 1e-5f) * bf2f(wp[W_SNG + lane]) + bf2f(wp[W_SNB + lane]);
  buf2[rowoff*64 + lane] = f2bf(o);
}

// ---------------- Stage 3: FFN + LN, 32 rows per block ----------------------
__global__ __launch_bounds__(256) void k_ffn(
    const bf16* __restrict__ buf2, const bf16* __restrict__ wp,
    const void* __restrict__ tng_raw, void* __restrict__ outv)
{
  __shared__ float xr[32][64];
  __shared__ float hid[32][256];
  __shared__ float mu[32], rs[32];
  int t = threadIdx.x;
  int f32o = sniff_f32(tng_raw);
  size_t base = (size_t)blockIdx.x * 32 * 64;
  for (int i = t; i < 32*64; i += 256) xr[i>>6][i&63] = bf2f(buf2[base + i]);
  __syncthreads();
  {
    float acc[32];
    #pragma unroll
    for (int r = 0; r < 32; ++r) acc[r] = 0.f;
    for (int h = 0; h < 64; ++h) {
      float wv = bf2f(wp[W_FW1 + h*256 + t]);
      #pragma unroll
      for (int r = 0; r < 32; ++r) acc[r] += xr[r][h]*wv;
    }
    float b1 = bf2f(wp[W_FB1 + t]);
    #pragma unroll
    for (int r = 0; r < 32; ++r) hid[r][t] = gelu_f(acc[r] + b1);
  }
  __syncthreads();
  {
    int j = t & 63, rg = t >> 6;
    float acc2[8];
    #pragma unroll
    for (int r = 0; r < 8; ++r) acc2[r] = 0.f;
    for (int k = 0; k < 256; ++k) {
      float wv = bf2f(wp[W_FW2 + k*64 + j]);
      #pragma unroll
      for (int r = 0; r < 8; ++r) acc2[r] += hid[rg*8+r][k]*wv;
    }
    float b2 = bf2f(wp[W_FB2 + j]);
    #pragma unroll
    for (int r = 0; r < 8; ++r) {
      int row = rg*8 + r;
      xr[row][j] = xr[row][j] + acc2[r] + b2;
    }
  }
  __syncthreads();
  if (t < 32) {
    float m = 0.f;
    for (int h = 0; h < 64; ++h) m += xr[t][h];
    m *= (1.0f/64.0f);
    float v2 = 0.f;
    for (int h = 0; h < 64; ++h) { float d = xr[t][h]-m; v2 += d*d; }
    mu[t] = m; rs[t] = rsqrtf(v2*(1.0f/64.0f) + 1e-5f);
  }
  __syncthreads();
  for (int i = t; i < 32*64; i += 256) {
    int r = i >> 6, j = i & 63;
    float o = (xr[r][j]-mu[r])*rs[r]*bf2f(wp[W_FNG + j]) + bf2f(wp[W_FNB + j]);
    if (f32o) ((float*)outv)[base + i] = o;
    else      ((bf16*)outv)[base + i] = f2bf(o);
  }
}

extern "C" void kernel_launch(void* const* d_in, const int* in_sizes, int n_in,
                              void* d_out, int out_size, void* d_ws, size_t ws_size,
                              hipStream_t stream)
{
  const void* x   = d_in[0];
  const int*  ei  = (const int*)d_in[1];
  const void* tng = d_in[7];

  // workspace layout (total ~46.5 MB)
  char* w = (char*)d_ws;
  bf16* xnorm = (bf16*)(w);                   // 20,480,000 B  (xnorm; reused as buf2 after k_attn)
  bf16* buf1  = (bf16*)(w + 20480000);        // 20,480,000 B
  bf16* c_e   = (bf16*)(w + 40960000);        //  5,120,000 B
  bf16* wpack = (bf16*)(w + 46080000);        //    239,552 B
  int* deg    = (int*) (w + 46320128);        // 20,000 B
  int* row_st = (int*) (w + 46340160);        // 20,004 B
  int* cursor = (int*) (w + 46360192);        // 20,000 B
  int* sorted = (int*) (w + 46380224);        // 80,000 B -> end 46,460,224

  bf16* buf2 = xnorm;  // xnorm is dead after k_attn; stage-2 output goes here

  WPtrs wps;
  for (int i = 0; i < 27; ++i) wps.p[i] = d_in[2 + i];

  hipMemsetAsync(deg,    0, Nn*sizeof(int), stream);
  hipMemsetAsync(cursor, 0, Nn*sizeof(int), stream);

  k_norm_x<<<XN/256, 256, 0, stream>>>(x, tng, xnorm);
  k_norm_w<<<(W_TOT+255)/256, 256, 0, stream>>>(wps, tng, wpack);
  k_attn<<<Bb*Nn, 256, 0, stream>>>(xnorm, wpack, buf1);
  k_edge<<<Ee, 128, 0, stream>>>(wpack, c_e);
  k_deg <<<(Ee+255)/256, 256, 0, stream>>>(ei, deg);
  k_scan<<<1, 256, 0, stream>>>(deg, row_st);
  k_fill<<<(Ee+255)/256, 256, 0, stream>>>(ei, row_st, cursor, sorted);
  k_msg_upd<<<ROWS/4, 256, 0, stream>>>(ei, row_st, sorted, c_e, wpack, buf1, buf2);
  k_ffn <<<ROWS/32, 256, 0, stream>>>(buf2, wpack, tng, d_out);
}

// Round 5
// 1378.786 us; speedup vs baseline: 1.8111x; 1.8111x over previous
//
#include <hip/hip_runtime.h>
#include <hip/hip_bf16.h>
#include <math.h>

#define Bb 2
#define Ss 16
#define Nn 5000
#define Hh 64
#define Ee 20000
#define BSn (Bb*Ss)          // 32
#define ROWS (BSn*Nn)        // 160000
#define XN 10240000          // B*S*N*H elements

typedef __hip_bfloat16 bf16;

__device__ __forceinline__ float bf2f(bf16 v){ return __bfloat162float(v); }
__device__ __forceinline__ bf16 f2bf(float v){ return __float2bfloat16(v); }
__device__ __forceinline__ float bfu(unsigned short u){ return __uint_as_float(((unsigned)u) << 16); }
__device__ __forceinline__ float gelu_f(float x){
  return 0.5f*x*(1.0f + erff(x*0.70710678118654752f));
}
__device__ __forceinline__ int sniff_f32(const void* tng){
  // tn_g is all-ones. fp32 1.0 little-endian -> first u16 = 0x0000; bf16 1.0 -> 0x3F80
  return (((const unsigned short*)tng)[0] == 0) ? 1 : 0;
}
__device__ __forceinline__ float rl(float v, int l){
  return __uint_as_float(__builtin_amdgcn_readlane(__float_as_uint(v), l));
}

// packed-weight element offsets (order = d_in[2..28])
#define W_EA   0
#define W_INW  20000
#define W_INB  32288
#define W_OW   32480
#define W_OB   36576
#define W_TNG  36640
#define W_TNB  36704
#define W_EW1  36768
#define W_EB1  36832
#define W_EW2  36896
#define W_EB2  40992
#define W_MW1  41056
#define W_MB1  65632
#define W_MW2  65760
#define W_MB2  73952
#define W_UW1  74016
#define W_UB1  82208
#define W_UW2  82272
#define W_UB2  86368
#define W_SNG  86432
#define W_SNB  86496
#define W_FW1  86560
#define W_FB1  102944
#define W_FW2  103200
#define W_FB2  119584
#define W_FNG  119648
#define W_FNB  119712
#define W_TOT  119776

// ---------------- normalize x -> bf16 ---------------------------------------
__global__ __launch_bounds__(256) void k_norm_x(const void* __restrict__ x,
                                                const void* __restrict__ tng,
                                                bf16* __restrict__ xn){
  int f32 = sniff_f32(tng);
  size_t i = (size_t)blockIdx.x*256 + threadIdx.x;   // grid covers XN exactly
  if (f32) xn[i] = f2bf(((const float*)x)[i]);
  else     xn[i] = ((const bf16*)x)[i];
}

// ---------------- normalize all weights -> packed bf16 ----------------------
struct WPtrs { const void* p[27]; };
__global__ __launch_bounds__(256) void k_norm_w(WPtrs wp_in, const void* __restrict__ tng,
                                                bf16* __restrict__ out){
  const int wseg[27] = {20000,12288,192,4096,64,64,64,64,64,4096,64,24576,128,8192,64,
                        8192,64,4096,64,64,64,16384,256,16384,64,64,64};
  int f32 = sniff_f32(tng);
  int i = blockIdx.x*256 + threadIdx.x;
  if (i >= W_TOT) return;
  int seg = 0, off = i;
  while (off >= wseg[seg]) { off -= wseg[seg]; ++seg; }
  const void* p = wp_in.p[seg];
  out[i] = f32 ? f2bf(((const float*)p)[off]) : ((const bf16*)p)[off];
}

// ---------------- Stage 1: temporal attention + LN, one block per (b,n) ----
__global__ __launch_bounds__(256) void k_attn(
    const bf16* __restrict__ xn, const bf16* __restrict__ wp, bf16* __restrict__ buf1)
{
  __shared__ float xt[16][64];
  __shared__ float qq[16][64];
  __shared__ float kk[16][64];
  __shared__ float vsm[16][64];
  __shared__ float ao[16][64];
  __shared__ float mu[16], rs[16];
  int t = threadIdx.x;
  int b = blockIdx.x / Nn, n = blockIdx.x - b*Nn;
  for (int i = t; i < 16*64; i += 256) {
    int s = i >> 6, h = i & 63;
    xt[s][h] = bf2f(xn[(((size_t)(b*Ss+s))*Nn + n)*64 + h]);
  }
  __syncthreads();
  for (int i = t; i < 16*192; i += 256) {
    int s = i / 192, j = i - s*192;
    float acc = bf2f(wp[W_INB + j]);
    for (int h = 0; h < 64; ++h) acc += xt[s][h]*bf2f(wp[W_INW + h*192 + j]);
    if (j < 64) qq[s][j] = acc;
    else if (j < 128) kk[s][j-64] = acc;
    else vsm[s][j-128] = acc;
  }
  __syncthreads();
  if (t < 64) {
    int hd = t >> 4, sq = t & 15;
    float sc[16]; float mx = -3.0e38f;
    #pragma unroll
    for (int sk = 0; sk < 16; ++sk) {
      float a = 0.f;
      #pragma unroll
      for (int d = 0; d < 16; ++d) a += qq[sq][hd*16+d]*kk[sk][hd*16+d];
      a *= 0.25f;
      sc[sk] = a; mx = fmaxf(mx, a);
    }
    float ssum = 0.f;
    #pragma unroll
    for (int sk = 0; sk < 16; ++sk) { sc[sk] = expf(sc[sk]-mx); ssum += sc[sk]; }
    float inv = 1.0f/ssum;
    #pragma unroll
    for (int d = 0; d < 16; ++d) {
      float a = 0.f;
      #pragma unroll
      for (int sk = 0; sk < 16; ++sk) a += sc[sk]*vsm[sk][hd*16+d];
      ao[sq][hd*16+d] = a*inv;
    }
  }
  __syncthreads();
  for (int i = t; i < 16*64; i += 256) {
    int s = i >> 6, j = i & 63;
    float acc = bf2f(wp[W_OB + j]);
    for (int h = 0; h < 64; ++h) acc += ao[s][h]*bf2f(wp[W_OW + h*64 + j]);
    qq[s][j] = xt[s][j] + acc;
  }
  __syncthreads();
  if (t < 16) {
    float m = 0.f;
    for (int h = 0; h < 64; ++h) m += qq[t][h];
    m *= (1.0f/64.0f);
    float v2 = 0.f;
    for (int h = 0; h < 64; ++h) { float d = qq[t][h]-m; v2 += d*d; }
    mu[t] = m; rs[t] = rsqrtf(v2*(1.0f/64.0f) + 1e-5f);
  }
  __syncthreads();
  for (int i = t; i < 16*64; i += 256) {
    int s = i >> 6, j = i & 63;
    float o = (qq[s][j]-mu[s])*rs[s]*bf2f(wp[W_TNG + j]) + bf2f(wp[W_TNB + j]);
    buf1[(((size_t)(b*Ss+s))*Nn + n)*64 + j] = f2bf(o);
  }
}

// ---------------- Stage 2b: P = ln1_out @ (Wa - Wb), 16 rows per block -----
// P lives in d_out (40.96 MB bf16 == out_size fp32 bytes); dead before k_ffn.
__global__ __launch_bounds__(256) void k_p(
    const bf16* __restrict__ buf1, const bf16* __restrict__ wp, bf16* __restrict__ P)
{
  __shared__ float wd[64][128];   // Wa - Wb, 32 KB
  __shared__ float xs[16][64];
  int t = threadIdx.x;
  for (int i = t; i < 64*128; i += 256) {
    int h = i >> 7, j = i & 127;
    wd[h][j] = bf2f(wp[W_MW1 + h*128 + j]) - bf2f(wp[W_MW1 + (64+h)*128 + j]);
  }
  size_t base  = (size_t)blockIdx.x * 16 * 64;
  size_t base2 = (size_t)blockIdx.x * 16 * 128;
  for (int i = t; i < 16*64; i += 256) xs[i>>6][i&63] = bf2f(buf1[base + i]);
  __syncthreads();
  int j = t & 127, rg = t >> 7;   // rg in {0,1}; 8 rows per thread
  float acc[8];
  #pragma unroll
  for (int r = 0; r < 8; ++r) acc[r] = 0.f;
  for (int h = 0; h < 64; ++h) {
    float wv = wd[h][j];
    #pragma unroll
    for (int r = 0; r < 8; ++r) acc[r] += xs[rg*8+r][h]*wv;
  }
  #pragma unroll
  for (int r = 0; r < 8; ++r) P[base2 + (size_t)(rg*8+r)*128 + j] = f2bf(acc[r]);
}

// ---------------- Stage 2a: edge embedding -> c_e = m_b1 + edge_emb @ Wc ----
__global__ __launch_bounds__(128) void k_edge(
    const bf16* __restrict__ wp, bf16* __restrict__ c_e)
{
  int e = blockIdx.x;
  __shared__ float tmp[64], emb[64];
  int t = threadIdx.x;
  float a = bf2f(wp[W_EA + e]);
  if (t < 64) tmp[t] = gelu_f(a*bf2f(wp[W_EW1 + t]) + bf2f(wp[W_EB1 + t]));
  __syncthreads();
  if (t < 64) {
    float acc = bf2f(wp[W_EB2 + t]);
    for (int h = 0; h < 64; ++h) acc += tmp[h]*bf2f(wp[W_EW2 + h*64 + t]);
    emb[t] = acc;
  }
  __syncthreads();
  float acc = bf2f(wp[W_MB1 + t]);
  for (int h = 0; h < 64; ++h) acc += emb[h]*bf2f(wp[W_MW1 + (128+h)*128 + t]);
  c_e[(size_t)e*128 + t] = f2bf(acc);
}

// ---------------- CSR build ------------------------------------------------
__global__ void k_deg(const int* __restrict__ ei, int* __restrict__ deg){
  int e = blockIdx.x*256 + threadIdx.x;
  if (e < Ee) atomicAdd(&deg[ei[Ee + e]], 1);
}

__global__ __launch_bounds__(256) void k_scan(const int* __restrict__ deg, int* __restrict__ row_st){
  __shared__ int part[256];
  int t = threadIdx.x;
  int base = t*20;
  int s = 0;
  for (int i = 0; i < 20; ++i) { int idx = base+i; if (idx < Nn) s += deg[idx]; }
  part[t] = s;
  __syncthreads();
  for (int off = 1; off < 256; off <<= 1) {
    int v = (t >= off) ? part[t-off] : 0;
    __syncthreads();
    part[t] += v;
    __syncthreads();
  }
  int run = (t == 0) ? 0 : part[t-1];
  for (int i = 0; i < 20; ++i) {
    int idx = base + i;
    if (idx < Nn) { row_st[idx] = run; run += deg[idx]; }
    else if (idx == Nn) { row_st[Nn] = run; }
  }
}

__global__ void k_fill(const int* __restrict__ ei, const int* __restrict__ row_st,
                       int* __restrict__ cursor, int* __restrict__ sorted){
  int e = blockIdx.x*256 + threadIdx.x;
  if (e >= Ee) return;
  int d = ei[Ee + e];
  int pos = atomicAdd(&cursor[d], 1);
  sorted[row_st[d] + pos] = e;
}

// ---------------- Stage 2c: edge gather+gelu+segsum, m_w2, update MLP, LN ---
// one wave per segment (bs,n); lane l owns hidden cols 2l, 2l+1 (bf16-pair
// loads of P[src] and c_e[e] rows: one uint per lane, 256 B/wave coalesced).
// Reads buf1, writes buf2 (no in-place: cross-block gather race, see R3).
__global__ __launch_bounds__(256) void k_msg_upd(
    const int* __restrict__ ei, const int* __restrict__ row_st, const int* __restrict__ sorted,
    const bf16* __restrict__ c_e, const bf16* __restrict__ wp,
    const bf16* __restrict__ buf1, const bf16* __restrict__ P, bf16* __restrict__ buf2)
{
  __shared__ unsigned wbl2[64][64];  // Wb packed bf16-pairs, 16 KB
  __shared__ float hsum[4][128];
  __shared__ float upd[4][128];
  int t = threadIdx.x;
  int w = t >> 6, lane = t & 63;
  for (int i = t; i < 64*64; i += 256) {
    int h = i >> 6, l = i & 63;
    wbl2[h][l] = ((const unsigned*)(wp + W_MW1 + (64+h)*128))[l];
  }
  int sid = blockIdx.x*4 + w;
  int bs = sid / Nn, n = sid - bs*Nn;
  size_t rowoff = (size_t)(bs*Nn + n);
  float xi = bf2f(buf1[rowoff*64 + lane]);
  __syncthreads();
  // Q for cols 2*lane, 2*lane+1 (x_i broadcast via readlane, Wb pairs from LDS)
  float q0 = 0.f, q1 = 0.f;
  #pragma unroll
  for (int h = 0; h < 64; ++h) {
    float xv = rl(xi, h);
    unsigned wpair = wbl2[h][lane];
    q0 += xv*bfu((unsigned short)wpair);
    q1 += xv*bfu((unsigned short)(wpair >> 16));
  }
  const unsigned* Pb = (const unsigned*)P + (size_t)bs*Nn*64;  // row stride 128 bf16 = 64 uints
  const unsigned* Cb = (const unsigned*)c_e;
  int s0 = row_st[n], s1 = row_st[n+1];
  float a0 = 0.f, a1 = 0.f;
  for (int ii = s0; ii < s1; ++ii) {
    int e = sorted[ii];
    int src = ei[e];
    unsigned pv = Pb[(size_t)src*64 + lane];
    unsigned cv = Cb[(size_t)e*64 + lane];
    a0 += gelu_f(bfu((unsigned short)pv)         + q0 + bfu((unsigned short)cv));
    a1 += gelu_f(bfu((unsigned short)(pv >> 16)) + q1 + bfu((unsigned short)(cv >> 16)));
  }
  ((float2*)hsum[w])[lane] = make_float2(a0, a1);   // cols 2l, 2l+1
  __syncthreads();
  float deg_f = (float)(s1 - s0);
  float aggr = deg_f * bf2f(wp[W_MB2 + lane]);
  for (int k = 0; k < 128; ++k) aggr += hsum[w][k]*bf2f(wp[W_MW2 + k*64 + lane]);
  upd[w][lane]    = xi;
  upd[w][64+lane] = aggr;
  __syncthreads();
  float hu = bf2f(wp[W_UB1 + lane]);
  for (int i = 0; i < 128; ++i) hu += upd[w][i]*bf2f(wp[W_UW1 + i*64 + lane]);
  hu = gelu_f(hu);
  __syncthreads();
  hsum[w][lane] = hu;
  __syncthreads();
  float sp = bf2f(wp[W_UB2 + lane]);
  for (int k = 0; k < 64; ++k) sp += hsum[w][k]*bf2f(wp[W_UW2 + k*64 + lane]);
  float resid = xi + sp;
  float m = resid;
  for (int off = 32; off > 0; off >>= 1) m += __shfl_xor(m, off, 64);
  m *= (1.0f/64.0f);
  float d = resid - m;
  float vv = d*d;
  for (int off = 32; off > 0; off >>= 1) vv += __shfl_xor(vv, off, 64);
  vv *= (1.0f/64.0f);
  float o = d * rsqrtf(vv + 1e-5f) * bf2f(wp[W_SNG + lane]) + bf2f(wp[W_SNB + lane]);
  buf2[rowoff*64 + lane] = f2bf(o);
}

// ---------------- Stage 3: FFN + LN, 32 rows per block ----------------------
__global__ __launch_bounds__(256) void k_ffn(
    const bf16* __restrict__ buf2, const bf16* __restrict__ wp,
    const void* __restrict__ tng_raw, void* __restrict__ outv)
{
  __shared__ float xr[32][64];
  __shared__ float hid[32][256];
  __shared__ float mu[32], rs[32];
  int t = threadIdx.x;
  int f32o = sniff_f32(tng_raw);
  size_t base = (size_t)blockIdx.x * 32 * 64;
  for (int i = t; i < 32*64; i += 256) xr[i>>6][i&63] = bf2f(buf2[base + i]);
  __syncthreads();
  {
    float acc[32];
    #pragma unroll
    for (int r = 0; r < 32; ++r) acc[r] = 0.f;
    for (int h = 0; h < 64; ++h) {
      float wv = bf2f(wp[W_FW1 + h*256 + t]);
      #pragma unroll
      for (int r = 0; r < 32; ++r) acc[r] += xr[r][h]*wv;
    }
    float b1 = bf2f(wp[W_FB1 + t]);
    #pragma unroll
    for (int r = 0; r < 32; ++r) hid[r][t] = gelu_f(acc[r] + b1);
  }
  __syncthreads();
  {
    int j = t & 63, rg = t >> 6;
    float acc2[8];
    #pragma unroll
    for (int r = 0; r < 8; ++r) acc2[r] = 0.f;
    for (int k = 0; k < 256; ++k) {
      float wv = bf2f(wp[W_FW2 + k*64 + j]);
      #pragma unroll
      for (int r = 0; r < 8; ++r) acc2[r] += hid[rg*8+r][k]*wv;
    }
    float b2 = bf2f(wp[W_FB2 + j]);
    #pragma unroll
    for (int r = 0; r < 8; ++r) {
      int row = rg*8 + r;
      xr[row][j] = xr[row][j] + acc2[r] + b2;
    }
  }
  __syncthreads();
  if (t < 32) {
    float m = 0.f;
    for (int h = 0; h < 64; ++h) m += xr[t][h];
    m *= (1.0f/64.0f);
    float v2 = 0.f;
    for (int h = 0; h < 64; ++h) { float d = xr[t][h]-m; v2 += d*d; }
    mu[t] = m; rs[t] = rsqrtf(v2*(1.0f/64.0f) + 1e-5f);
  }
  __syncthreads();
  for (int i = t; i < 32*64; i += 256) {
    int r = i >> 6, j = i & 63;
    float o = (xr[r][j]-mu[r])*rs[r]*bf2f(wp[W_FNG + j]) + bf2f(wp[W_FNB + j]);
    if (f32o) ((float*)outv)[base + i] = o;
    else      ((bf16*)outv)[base + i] = f2bf(o);
  }
}

extern "C" void kernel_launch(void* const* d_in, const int* in_sizes, int n_in,
                              void* d_out, int out_size, void* d_ws, size_t ws_size,
                              hipStream_t stream)
{
  const void* x   = d_in[0];
  const int*  ei  = (const int*)d_in[1];
  const void* tng = d_in[7];

  // workspace layout (total ~46.5 MB)
  char* w = (char*)d_ws;
  bf16* xnorm = (bf16*)(w);                   // 20,480,000 B (dead after k_attn -> buf2)
  bf16* buf1  = (bf16*)(w + 20480000);        // 20,480,000 B
  bf16* c_e   = (bf16*)(w + 40960000);        //  5,120,000 B
  bf16* wpack = (bf16*)(w + 46080000);        //    239,552 B
  int* deg    = (int*) (w + 46320128);        // 20,000 B
  int* row_st = (int*) (w + 46340160);        // 20,004 B
  int* cursor = (int*) (w + 46360192);        // 20,000 B
  int* sorted = (int*) (w + 46380224);        // 80,000 B -> end 46,460,224

  bf16* buf2 = xnorm;        // stage-2 output
  bf16* P    = (bf16*)d_out; // 20,480,000 bf16 = 40.96 MB, exactly out_size*4 B;
                             // dead before k_ffn overwrites d_out (stream-ordered)

  WPtrs wps;
  for (int i = 0; i < 27; ++i) wps.p[i] = d_in[2 + i];

  hipMemsetAsync(deg,    0, Nn*sizeof(int), stream);
  hipMemsetAsync(cursor, 0, Nn*sizeof(int), stream);

  k_norm_x<<<XN/256, 256, 0, stream>>>(x, tng, xnorm);
  k_norm_w<<<(W_TOT+255)/256, 256, 0, stream>>>(wps, tng, wpack);
  k_attn<<<Bb*Nn, 256, 0, stream>>>(xnorm, wpack, buf1);
  k_p   <<<ROWS/16, 256, 0, stream>>>(buf1, wpack, P);
  k_edge<<<Ee, 128, 0, stream>>>(wpack, c_e);
  k_deg <<<(Ee+255)/256, 256, 0, stream>>>(ei, deg);
  k_scan<<<1, 256, 0, stream>>>(deg, row_st);
  k_fill<<<(Ee+255)/256, 256, 0, stream>>>(ei, row_st, cursor, sorted);
  k_msg_upd<<<ROWS/4, 256, 0, stream>>>(ei, row_st, sorted, c_e, wpack, buf1, P, buf2);
  k_ffn <<<ROWS/32, 256, 0, stream>>>(buf2, wpack, tng, d_out);
}

// Round 7
// 920.997 us; speedup vs baseline: 2.7114x; 1.4971x over previous
//
#include <hip/hip_runtime.h>
#include <hip/hip_bf16.h>
#include <math.h>

#define Bb 2
#define Ss 16
#define Nn 5000
#define Hh 64
#define Ee 20000
#define BSn (Bb*Ss)          // 32
#define ROWS (BSn*Nn)        // 160000
#define XN 10240000          // B*S*N*H elements

typedef __hip_bfloat16 bf16;
typedef __attribute__((ext_vector_type(8))) short bfrag;   // 8 bf16 (4 VGPRs)
typedef __attribute__((ext_vector_type(4))) float f32x4;   // MFMA acc

__device__ __forceinline__ float bf2f(bf16 v){ return __bfloat162float(v); }
__device__ __forceinline__ bf16 f2bf(float v){ return __float2bfloat16(v); }
__device__ __forceinline__ float bfu(unsigned short u){ return __uint_as_float(((unsigned)u) << 16); }
__device__ __forceinline__ float gelu_f(float x){
  return 0.5f*x*(1.0f + erff(x*0.70710678118654752f));
}
__device__ __forceinline__ int sniff_f32(const void* tng){
  return (((const unsigned short*)tng)[0] == 0) ? 1 : 0;   // tn_g all-ones
}
__device__ __forceinline__ float rl(float v, int l){
  return __uint_as_float(__builtin_amdgcn_readlane(__float_as_uint(v), l));
}

// packed-weight element offsets (order = d_in[2..28])
#define W_EA   0
#define W_INW  20000
#define W_INB  32288
#define W_OW   32480
#define W_OB   36576
#define W_TNG  36640
#define W_TNB  36704
#define W_EW1  36768
#define W_EB1  36832
#define W_EW2  36896
#define W_EB2  40992
#define W_MW1  41056
#define W_MB1  65632
#define W_MW2  65760
#define W_MB2  73952
#define W_UW1  74016
#define W_UB1  82208
#define W_UW2  82272
#define W_UB2  86368
#define W_SNG  86432
#define W_SNB  86496
#define W_FW1  86560
#define W_FB1  102944
#define W_FW2  103200
#define W_FB2  119584
#define W_FNG  119648
#define W_FNB  119712
#define W_TOT  119776

// ---------------- normalize x -> bf16 ---------------------------------------
__global__ __launch_bounds__(256) void k_norm_x(const void* __restrict__ x,
                                                const void* __restrict__ tng,
                                                bf16* __restrict__ xn){
  int f32 = sniff_f32(tng);
  size_t i = (size_t)blockIdx.x*256 + threadIdx.x;
  if (f32) xn[i] = f2bf(((const float*)x)[i]);
  else     xn[i] = ((const bf16*)x)[i];
}

// ---------------- normalize all weights -> packed bf16 ----------------------
struct WPtrs { const void* p[27]; };
__global__ __launch_bounds__(256) void k_norm_w(WPtrs wp_in, const void* __restrict__ tng,
                                                bf16* __restrict__ out){
  const int wseg[27] = {20000,12288,192,4096,64,64,64,64,64,4096,64,24576,128,8192,64,
                        8192,64,4096,64,64,64,16384,256,16384,64,64,64};
  int f32 = sniff_f32(tng);
  int i = blockIdx.x*256 + threadIdx.x;
  if (i >= W_TOT) return;
  int seg = 0, off = i;
  while (off >= wseg[seg]) { off -= wseg[seg]; ++seg; }
  const void* p = wp_in.p[seg];
  out[i] = f32 ? f2bf(((const float*)p)[off]) : ((const bf16*)p)[off];
}

// ---------------- Stage 1: temporal attention + LN, one block per (b,n) ----
__global__ __launch_bounds__(256) void k_attn(
    const bf16* __restrict__ xn, const bf16* __restrict__ wp, bf16* __restrict__ buf1)
{
  __shared__ float xt[16][64];
  __shared__ float qq[16][64];
  __shared__ float kk[16][64];
  __shared__ float vsm[16][64];
  __shared__ float ao[16][64];
  __shared__ float mu[16], rs[16];
  int t = threadIdx.x;
  int b = blockIdx.x / Nn, n = blockIdx.x - b*Nn;
  for (int i = t; i < 16*64; i += 256) {
    int s = i >> 6, h = i & 63;
    xt[s][h] = bf2f(xn[(((size_t)(b*Ss+s))*Nn + n)*64 + h]);
  }
  __syncthreads();
  for (int i = t; i < 16*192; i += 256) {
    int s = i / 192, j = i - s*192;
    float acc = bf2f(wp[W_INB + j]);
    for (int h = 0; h < 64; ++h) acc += xt[s][h]*bf2f(wp[W_INW + h*192 + j]);
    if (j < 64) qq[s][j] = acc;
    else if (j < 128) kk[s][j-64] = acc;
    else vsm[s][j-128] = acc;
  }
  __syncthreads();
  if (t < 64) {
    int hd = t >> 4, sq = t & 15;
    float sc[16]; float mx = -3.0e38f;
    #pragma unroll
    for (int sk = 0; sk < 16; ++sk) {
      float a = 0.f;
      #pragma unroll
      for (int d = 0; d < 16; ++d) a += qq[sq][hd*16+d]*kk[sk][hd*16+d];
      a *= 0.25f;
      sc[sk] = a; mx = fmaxf(mx, a);
    }
    float ssum = 0.f;
    #pragma unroll
    for (int sk = 0; sk < 16; ++sk) { sc[sk] = expf(sc[sk]-mx); ssum += sc[sk]; }
    float inv = 1.0f/ssum;
    #pragma unroll
    for (int d = 0; d < 16; ++d) {
      float a = 0.f;
      #pragma unroll
      for (int sk = 0; sk < 16; ++sk) a += sc[sk]*vsm[sk][hd*16+d];
      ao[sq][hd*16+d] = a*inv;
    }
  }
  __syncthreads();
  for (int i = t; i < 16*64; i += 256) {
    int s = i >> 6, j = i & 63;
    float acc = bf2f(wp[W_OB + j]);
    for (int h = 0; h < 64; ++h) acc += ao[s][h]*bf2f(wp[W_OW + h*64 + j]);
    qq[s][j] = xt[s][j] + acc;
  }
  __syncthreads();
  if (t < 16) {
    float m = 0.f;
    for (int h = 0; h < 64; ++h) m += qq[t][h];
    m *= (1.0f/64.0f);
    float v2 = 0.f;
    for (int h = 0; h < 64; ++h) { float d = qq[t][h]-m; v2 += d*d; }
    mu[t] = m; rs[t] = rsqrtf(v2*(1.0f/64.0f) + 1e-5f);
  }
  __syncthreads();
  for (int i = t; i < 16*64; i += 256) {
    int s = i >> 6, j = i & 63;
    float o = (qq[s][j]-mu[s])*rs[s]*bf2f(wp[W_TNG + j]) + bf2f(wp[W_TNB + j]);
    buf1[(((size_t)(b*Ss+s))*Nn + n)*64 + j] = f2bf(o);
  }
}

// ---------------- swizzle Wa-Wb into B-frag layout (for k_p) ----------------
__global__ __launch_bounds__(256) void k_swz_wd(const bf16* __restrict__ wp,
                                                bf16* __restrict__ swd){
  int i = blockIdx.x*256 + threadIdx.x;   // 8192
  int j = i & 7, lane = (i >> 3) & 63, fi = i >> 9;  // fi = ks*8+ct
  int ct = fi & 7, ks = fi >> 3;
  int k = 32*ks + (lane >> 4)*8 + j;
  int nn = 16*ct + (lane & 15);
  swd[i] = f2bf(bf2f(wp[W_MW1 + k*128 + nn]) - bf2f(wp[W_MW1 + (64+k)*128 + nn]));
}

// ---------------- swizzle uw1/uw2/fw1/fw2 into B-frag layout (for k_upd) ----
__global__ __launch_bounds__(256) void k_swz_upd(const bf16* __restrict__ wp,
                                                 bf16* __restrict__ swz){
  int i = blockIdx.x*256 + threadIdx.x;   // 45056
  if (i >= 45056) return;
  int base, CT, N, woff;
  if      (i < 8192)  { base=0;     CT=4;  N=64;  woff=W_UW1; }
  else if (i < 12288) { base=8192;  CT=4;  N=64;  woff=W_UW2; }
  else if (i < 28672) { base=12288; CT=16; N=256; woff=W_FW1; }
  else                { base=28672; CT=4;  N=64;  woff=W_FW2; }
  int loc = i - base;
  int j = loc & 7, lane = (loc >> 3) & 63, fi = loc >> 9;
  int ct = fi % CT, ks = fi / CT;
  int k = 32*ks + (lane >> 4)*8 + j;
  int nn = 16*ct + (lane & 15);
  swz[i] = wp[woff + k*N + nn];
}

// ---------------- Stage 2b: P = ln1_out @ (Wa-Wb) via MFMA, 64 rows/block ---
__global__ __launch_bounds__(256) void k_p(
    const bf16* __restrict__ buf1, const bf16* __restrict__ swd, bf16* __restrict__ P)
{
  __shared__ __align__(16) short xst[64][72];
  int t = threadIdx.x;
  int w = t >> 6, lane = t & 63, quad = lane >> 4, l15 = lane & 15;
  size_t rowbase = (size_t)blockIdx.x * 64;
  const unsigned* bx = (const unsigned*)(buf1 + rowbase*64);
  for (int i = t; i < 2048; i += 256) {
    int r = i >> 5, cu = i & 31;
    *(unsigned*)&xst[r][2*cu] = bx[i];
  }
  __syncthreads();
  int row0 = w*16;
  bfrag a[2];
  #pragma unroll
  for (int ks = 0; ks < 2; ++ks)
    a[ks] = *(const bfrag*)&xst[row0 + l15][32*ks + quad*8];
  const bfrag* SW = (const bfrag*)swd;
  #pragma unroll
  for (int ct = 0; ct < 8; ++ct) {
    f32x4 acc = {0.f,0.f,0.f,0.f};
    #pragma unroll
    for (int ks = 0; ks < 2; ++ks)
      acc = __builtin_amdgcn_mfma_f32_16x16x32_bf16(a[ks], SW[(ks*8+ct)*64 + lane], acc, 0,0,0);
    #pragma unroll
    for (int r = 0; r < 4; ++r) {
      int row = row0 + quad*4 + r, col = ct*16 + l15;
      P[(rowbase + row)*128 + col] = f2bf(acc[r]);
    }
  }
}

// ---------------- Stage 2a: edge embedding -> c_e = m_b1 + edge_emb @ Wc ----
__global__ __launch_bounds__(128) void k_edge(
    const bf16* __restrict__ wp, bf16* __restrict__ c_e)
{
  int e = blockIdx.x;
  __shared__ float tmp[64], emb[64];
  int t = threadIdx.x;
  float a = bf2f(wp[W_EA + e]);
  if (t < 64) tmp[t] = gelu_f(a*bf2f(wp[W_EW1 + t]) + bf2f(wp[W_EB1 + t]));
  __syncthreads();
  if (t < 64) {
    float acc = bf2f(wp[W_EB2 + t]);
    for (int h = 0; h < 64; ++h) acc += tmp[h]*bf2f(wp[W_EW2 + h*64 + t]);
    emb[t] = acc;
  }
  __syncthreads();
  float acc = bf2f(wp[W_MB1 + t]);
  for (int h = 0; h < 64; ++h) acc += emb[h]*bf2f(wp[W_MW1 + (128+h)*128 + t]);
  c_e[(size_t)e*128 + t] = f2bf(acc);
}

// ---------------- CSR build ------------------------------------------------
__global__ void k_deg(const int* __restrict__ ei, int* __restrict__ deg){
  int e = blockIdx.x*256 + threadIdx.x;
  if (e < Ee) atomicAdd(&deg[ei[Ee + e]], 1);
}

__global__ __launch_bounds__(256) void k_scan(const int* __restrict__ deg, int* __restrict__ row_st){
  __shared__ int part[256];
  int t = threadIdx.x;
  int base = t*20;
  int s = 0;
  for (int i = 0; i < 20; ++i) { int idx = base+i; if (idx < Nn) s += deg[idx]; }
  part[t] = s;
  __syncthreads();
  for (int off = 1; off < 256; off <<= 1) {
    int v = (t >= off) ? part[t-off] : 0;
    __syncthreads();
    part[t] += v;
    __syncthreads();
  }
  int run = (t == 0) ? 0 : part[t-1];
  for (int i = 0; i < 20; ++i) {
    int idx = base + i;
    if (idx < Nn) { row_st[idx] = run; run += deg[idx]; }
    else if (idx == Nn) { row_st[Nn] = run; }
  }
}

__global__ void k_fill(const int* __restrict__ ei, const int* __restrict__ row_st,
                       int* __restrict__ cursor, int* __restrict__ sorted){
  int e = blockIdx.x*256 + threadIdx.x;
  if (e >= Ee) return;
  int d = ei[Ee + e];
  int pos = atomicAdd(&cursor[d], 1);
  sorted[row_st[d] + pos] = e;
}

// ---------------- Stage 2c: edge gather+gelu+segsum + mw2 -> aggr -----------
__global__ __launch_bounds__(256) void k_gather(
    const int* __restrict__ ei, const int* __restrict__ row_st, const int* __restrict__ sorted,
    const bf16* __restrict__ c_e, const bf16* __restrict__ wp,
    const bf16* __restrict__ buf1, const bf16* __restrict__ P, bf16* __restrict__ aggrbuf)
{
  __shared__ unsigned wbl2[64][64];  // Wb packed bf16-pairs, 16 KB
  __shared__ float hsum[4][128];
  int t = threadIdx.x;
  int w = t >> 6, lane = t & 63;
  for (int i = t; i < 64*64; i += 256) {
    int h = i >> 6, l = i & 63;
    wbl2[h][l] = ((const unsigned*)(wp + W_MW1 + (64+h)*128))[l];
  }
  int sid = blockIdx.x*4 + w;
  int bs = sid / Nn, n = sid - bs*Nn;
  size_t rowoff = (size_t)(bs*Nn + n);
  float xi = bf2f(buf1[rowoff*64 + lane]);
  __syncthreads();
  float q0 = 0.f, q1 = 0.f;
  #pragma unroll
  for (int h = 0; h < 64; ++h) {
    float xv = rl(xi, h);
    unsigned wpair = wbl2[h][lane];
    q0 += xv*bfu((unsigned short)wpair);
    q1 += xv*bfu((unsigned short)(wpair >> 16));
  }
  const unsigned* Pb = (const unsigned*)P + (size_t)bs*Nn*64;
  const unsigned* Cb = (const unsigned*)c_e;
  int s0 = row_st[n], s1 = row_st[n+1];
  float a0 = 0.f, a1 = 0.f;
  for (int ii = s0; ii < s1; ++ii) {
    int e = sorted[ii];
    int src = ei[e];
    unsigned pv = Pb[(size_t)src*64 + lane];
    unsigned cv = Cb[(size_t)e*64 + lane];
    a0 += gelu_f(bfu((unsigned short)pv)         + q0 + bfu((unsigned short)cv));
    a1 += gelu_f(bfu((unsigned short)(pv >> 16)) + q1 + bfu((unsigned short)(cv >> 16)));
  }
  ((float2*)hsum[w])[lane] = make_float2(a0, a1);
  __syncthreads();
  float deg_f = (float)(s1 - s0);
  float aggr = deg_f * bf2f(wp[W_MB2 + lane]);
  for (int k = 0; k < 128; ++k) aggr += hsum[w][k]*bf2f(wp[W_MW2 + k*64 + lane]);
  aggrbuf[rowoff*64 + lane] = f2bf(aggr);
}

// ---------------- Stage 2d+3: update MLP + LN2 + FFN + LN3 (MFMA) -----------
// 64 rows/block. Barriers between cross-lane LDS write->read phases: the
// compiler may hoist a ds_read above other lanes' ds_writes (per-thread alias
// analysis can't see cross-lane deps).
__global__ __launch_bounds__(256) void k_upd(
    const bf16* __restrict__ buf1, const bf16* __restrict__ aggrbuf,
    const bf16* __restrict__ swz, const bf16* __restrict__ wp,
    const void* __restrict__ tng_raw, void* __restrict__ outv)
{
  __shared__ __align__(16) short updt[64][136];  // cols 0..63 xs->xs2, 64..127 aggr->h2
  __shared__ __align__(16) short mid[64][264];   // FFN hidden 256
  int t = threadIdx.x;
  int w = t >> 6, lane = t & 63, quad = lane >> 4, l15 = lane & 15;
  int f32o = sniff_f32(tng_raw);
  size_t rowbase = (size_t)blockIdx.x * 64;
  const unsigned* bx = (const unsigned*)(buf1 + rowbase*64);
  const unsigned* ba = (const unsigned*)(aggrbuf + rowbase*64);
  for (int i = t; i < 2048; i += 256) {
    int r = i >> 5, cu = i & 31;
    *(unsigned*)&updt[r][2*cu]      = bx[i];
    *(unsigned*)&updt[r][64 + 2*cu] = ba[i];
  }
  __syncthreads();
  int row0 = w*16;
  const bfrag* SW = (const bfrag*)swz;  // uw1@0, uw2@1024, fw1@1536, fw2@3584 (frag idx)

  // ---- GEMM2: h2 = gelu([xs|aggr] @ uw1 + ub1), K=128 CT=4 ----
  bfrag a2[4];
  #pragma unroll
  for (int ks = 0; ks < 4; ++ks)
    a2[ks] = *(const bfrag*)&updt[row0 + l15][32*ks + quad*8];
  float h2v[4][4];
  #pragma unroll
  for (int ct = 0; ct < 4; ++ct) {
    f32x4 acc = {0.f,0.f,0.f,0.f};
    #pragma unroll
    for (int ks = 0; ks < 4; ++ks)
      acc = __builtin_amdgcn_mfma_f32_16x16x32_bf16(a2[ks], SW[(ks*4+ct)*64 + lane], acc, 0,0,0);
    float b1 = bf2f(wp[W_UB1 + ct*16 + l15]);
    #pragma unroll
    for (int r = 0; r < 4; ++r) h2v[ct][r] = gelu_f(acc[r] + b1);
  }
  #pragma unroll
  for (int ct = 0; ct < 4; ++ct)
    #pragma unroll
    for (int r = 0; r < 4; ++r)
      *(bf16*)&updt[row0 + quad*4 + r][64 + ct*16 + l15] = f2bf(h2v[ct][r]);
  __syncthreads();   // h2 cross-lane: writes (quad-row layout) -> a3 reads (l15-row)

  // ---- GEMM3: xs2 = LN2(xs + h2 @ uw2 + ub2), K=64 CT=4 ----
  bfrag a3[2];
  #pragma unroll
  for (int ks = 0; ks < 2; ++ks)
    a3[ks] = *(const bfrag*)&updt[row0 + l15][64 + 32*ks + quad*8];
  float xv[4][4];
  #pragma unroll
  for (int ct = 0; ct < 4; ++ct) {
    f32x4 acc = {0.f,0.f,0.f,0.f};
    #pragma unroll
    for (int ks = 0; ks < 2; ++ks)
      acc = __builtin_amdgcn_mfma_f32_16x16x32_bf16(a3[ks], SW[1024 + (ks*4+ct)*64 + lane], acc, 0,0,0);
    float b2 = bf2f(wp[W_UB2 + ct*16 + l15]);
    #pragma unroll
    for (int r = 0; r < 4; ++r)
      xv[ct][r] = acc[r] + b2 + bf2f(*(const bf16*)&updt[row0 + quad*4 + r][ct*16 + l15]);
  }
  {
    float g[4], bb[4];
    #pragma unroll
    for (int ct = 0; ct < 4; ++ct) { g[ct] = bf2f(wp[W_SNG + ct*16 + l15]); bb[ct] = bf2f(wp[W_SNB + ct*16 + l15]); }
    #pragma unroll
    for (int r = 0; r < 4; ++r) {
      float part = xv[0][r] + xv[1][r] + xv[2][r] + xv[3][r];
      part += __shfl_xor(part, 1, 64); part += __shfl_xor(part, 2, 64);
      part += __shfl_xor(part, 4, 64); part += __shfl_xor(part, 8, 64);
      float mean = part*(1.0f/64.0f);
      float p2 = 0.f;
      #pragma unroll
      for (int ct = 0; ct < 4; ++ct) { float d = xv[ct][r]-mean; p2 += d*d; }
      p2 += __shfl_xor(p2, 1, 64); p2 += __shfl_xor(p2, 2, 64);
      p2 += __shfl_xor(p2, 4, 64); p2 += __shfl_xor(p2, 8, 64);
      float rstd = rsqrtf(p2*(1.0f/64.0f) + 1e-5f);
      #pragma unroll
      for (int ct = 0; ct < 4; ++ct) {
        float xs2 = (xv[ct][r]-mean)*rstd*g[ct] + bb[ct];
        *(bf16*)&updt[row0 + quad*4 + r][ct*16 + l15] = f2bf(xs2);
      }
    }
  }
  __syncthreads();   // xs2 cross-lane -> a4 reads

  // ---- GEMM4: mid = gelu(xs2 @ fw1 + fb1), K=64 CT=16 ----
  bfrag a4[2];
  #pragma unroll
  for (int ks = 0; ks < 2; ++ks)
    a4[ks] = *(const bfrag*)&updt[row0 + l15][32*ks + quad*8];
  #pragma unroll
  for (int ct = 0; ct < 16; ++ct) {
    f32x4 acc = {0.f,0.f,0.f,0.f};
    #pragma unroll
    for (int ks = 0; ks < 2; ++ks)
      acc = __builtin_amdgcn_mfma_f32_16x16x32_bf16(a4[ks], SW[1536 + (ks*16+ct)*64 + lane], acc, 0,0,0);
    float b = bf2f(wp[W_FB1 + ct*16 + l15]);
    #pragma unroll
    for (int r = 0; r < 4; ++r)
      *(bf16*)&mid[row0 + quad*4 + r][ct*16 + l15] = f2bf(gelu_f(acc[r] + b));
  }
  __syncthreads();   // mid cross-lane -> a5 reads

  // ---- GEMM5: out = LN3(xs2 + mid @ fw2 + fb2), K=256 CT=4 ----
  bfrag a5[8];
  #pragma unroll
  for (int ks = 0; ks < 8; ++ks)
    a5[ks] = *(const bfrag*)&mid[row0 + l15][32*ks + quad*8];
  float ov[4][4];
  #pragma unroll
  for (int ct = 0; ct < 4; ++ct) {
    f32x4 acc = {0.f,0.f,0.f,0.f};
    #pragma unroll
    for (int ks = 0; ks < 8; ++ks)
      acc = __builtin_amdgcn_mfma_f32_16x16x32_bf16(a5[ks], SW[3584 + (ks*4+ct)*64 + lane], acc, 0,0,0);
    float b = bf2f(wp[W_FB2 + ct*16 + l15]);
    #pragma unroll
    for (int r = 0; r < 4; ++r)
      ov[ct][r] = acc[r] + b + bf2f(*(const bf16*)&updt[row0 + quad*4 + r][ct*16 + l15]);
  }
  {
    float g[4], bb[4];
    #pragma unroll
    for (int ct = 0; ct < 4; ++ct) { g[ct] = bf2f(wp[W_FNG + ct*16 + l15]); bb[ct] = bf2f(wp[W_FNB + ct*16 + l15]); }
    #pragma unroll
    for (int r = 0; r < 4; ++r) {
      float part = ov[0][r] + ov[1][r] + ov[2][r] + ov[3][r];
      part += __shfl_xor(part, 1, 64); part += __shfl_xor(part, 2, 64);
      part += __shfl_xor(part, 4, 64); part += __shfl_xor(part, 8, 64);
      float mean = part*(1.0f/64.0f);
      float p2 = 0.f;
      #pragma unroll
      for (int ct = 0; ct < 4; ++ct) { float d = ov[ct][r]-mean; p2 += d*d; }
      p2 += __shfl_xor(p2, 1, 64); p2 += __shfl_xor(p2, 2, 64);
      p2 += __shfl_xor(p2, 4, 64); p2 += __shfl_xor(p2, 8, 64);
      float rstd = rsqrtf(p2*(1.0f/64.0f) + 1e-5f);
      size_t rowg = rowbase + row0 + quad*4 + r;
      #pragma unroll
      for (int ct = 0; ct < 4; ++ct) {
        float o = (ov[ct][r]-mean)*rstd*g[ct] + bb[ct];
        size_t idx = rowg*64 + ct*16 + l15;
        if (f32o) ((float*)outv)[idx] = o;
        else      ((bf16*)outv)[idx] = f2bf(o);
      }
    }
  }
}

extern "C" void kernel_launch(void* const* d_in, const int* in_sizes, int n_in,
                              void* d_out, int out_size, void* d_ws, size_t ws_size,
                              hipStream_t stream)
{
  const void* x   = d_in[0];
  const int*  ei  = (const int*)d_in[1];
  const void* tng = d_in[7];

  // workspace layout: base 46.46 MB + optional P region (preferred)
  char* w = (char*)d_ws;
  bf16* xnorm  = (bf16*)(w);                   // 20,480,000 B; reused: swzwd then aggr
  bf16* buf1   = (bf16*)(w + 20480000);        // 20,480,000 B (LN1 out)
  bf16* c_e    = (bf16*)(w + 40960000);        //  5,120,000 B; reused: swzupd after k_gather
  bf16* wpack  = (bf16*)(w + 46080000);        //    239,552 B
  int* deg     = (int*) (w + 46320128);
  int* row_st  = (int*) (w + 46340160);
  int* cursor  = (int*) (w + 46360192);
  int* sorted  = (int*) (w + 46380224);        // end 46,460,224

  bf16* swzwd  = xnorm;          // 8192 els, alive k_swz_wd..k_p
  bf16* aggrb  = xnorm;          // gather output (full 20.48 MB)
  bf16* swzupd = c_e;            // 45056 els, alive k_swz_upd..k_upd

  // P (160000x128 bf16 = 40.96 MB): prefer d_ws (immune to harness d_out
  // re-poison timing); fall back to d_out scratch only if ws is too small.
  // ws_size is constant across calls -> same work every call.
  bf16* P = (ws_size >= (size_t)87424000) ? (bf16*)(w + 46464000)
                                          : (bf16*)d_out;

  WPtrs wps;
  for (int i = 0; i < 27; ++i) wps.p[i] = d_in[2 + i];

  hipMemsetAsync(deg,    0, Nn*sizeof(int), stream);
  hipMemsetAsync(cursor, 0, Nn*sizeof(int), stream);

  k_norm_x<<<XN/256, 256, 0, stream>>>(x, tng, xnorm);
  k_norm_w<<<(W_TOT+255)/256, 256, 0, stream>>>(wps, tng, wpack);
  k_attn<<<Bb*Nn, 256, 0, stream>>>(xnorm, wpack, buf1);
  k_swz_wd<<<8192/256, 256, 0, stream>>>(wpack, swzwd);
  k_p<<<ROWS/64, 256, 0, stream>>>(buf1, swzwd, P);
  k_edge<<<Ee, 128, 0, stream>>>(wpack, c_e);
  k_deg <<<(Ee+255)/256, 256, 0, stream>>>(ei, deg);
  k_scan<<<1, 256, 0, stream>>>(deg, row_st);
  k_fill<<<(Ee+255)/256, 256, 0, stream>>>(ei, row_st, cursor, sorted);
  k_gather<<<ROWS/4, 256, 0, stream>>>(ei, row_st, sorted, c_e, wpack, buf1, P, aggrb);
  k_swz_upd<<<(45056+255)/256, 256, 0, stream>>>(wpack, swzupd);
  k_upd<<<ROWS/64, 256, 0, stream>>>(buf1, aggrb, swzupd, wpack, tng, d_out);
}

// Round 8
// 557.250 us; speedup vs baseline: 4.4813x; 1.6528x over previous
//
#include <hip/hip_runtime.h>
#include <hip/hip_bf16.h>
#include <math.h>

#define Bb 2
#define Ss 16
#define Nn 5000
#define Hh 64
#define Ee 20000
#define BSn (Bb*Ss)          // 32
#define ROWS (BSn*Nn)        // 160000
#define XN 10240000          // B*S*N*H elements

typedef __hip_bfloat16 bf16;
typedef __attribute__((ext_vector_type(8))) short bfrag;   // 8 bf16 (4 VGPRs)
typedef __attribute__((ext_vector_type(4))) float f32x4;   // MFMA acc

__device__ __forceinline__ float bf2f(bf16 v){ return __bfloat162float(v); }
__device__ __forceinline__ bf16 f2bf(float v){ return __float2bfloat16(v); }
__device__ __forceinline__ float bfu(unsigned short u){ return __uint_as_float(((unsigned)u) << 16); }
__device__ __forceinline__ float gelu_f(float x){
  return 0.5f*x*(1.0f + erff(x*0.70710678118654752f));
}
__device__ __forceinline__ int sniff_f32(const void* tng){
  return (((const unsigned short*)tng)[0] == 0) ? 1 : 0;   // tn_g all-ones
}
__device__ __forceinline__ float rl(float v, int l){
  return __uint_as_float(__builtin_amdgcn_readlane(__float_as_uint(v), l));
}
__device__ __forceinline__ unsigned pack2(float a, float b){
  unsigned short u0, u1; bf16 b0 = f2bf(a), b1 = f2bf(b);
  u0 = *(unsigned short*)&b0; u1 = *(unsigned short*)&b1;
  return ((unsigned)u1 << 16) | u0;
}

// packed-weight element offsets (order = d_in[2..28])
#define W_EA   0
#define W_INW  20000
#define W_INB  32288
#define W_OW   32480
#define W_OB   36576
#define W_TNG  36640
#define W_TNB  36704
#define W_EW1  36768
#define W_EB1  36832
#define W_EW2  36896
#define W_EB2  40992
#define W_MW1  41056
#define W_MB1  65632
#define W_MW2  65760
#define W_MB2  73952
#define W_UW1  74016
#define W_UB1  82208
#define W_UW2  82272
#define W_UB2  86368
#define W_SNG  86432
#define W_SNB  86496
#define W_FW1  86560
#define W_FB1  102944
#define W_FW2  103200
#define W_FB2  119584
#define W_FNG  119648
#define W_FNB  119712
#define W_TOT  119776

// ---------------- normalize x -> bf16 ---------------------------------------
__global__ __launch_bounds__(256) void k_norm_x(const void* __restrict__ x,
                                                const void* __restrict__ tng,
                                                bf16* __restrict__ xn){
  int f32 = sniff_f32(tng);
  size_t i = (size_t)blockIdx.x*256 + threadIdx.x;
  if (f32) xn[i] = f2bf(((const float*)x)[i]);
  else     xn[i] = ((const bf16*)x)[i];
}

// ---------------- normalize all weights -> packed bf16 ----------------------
struct WPtrs { const void* p[27]; };
__global__ __launch_bounds__(256) void k_norm_w(WPtrs wp_in, const void* __restrict__ tng,
                                                bf16* __restrict__ out){
  const int wseg[27] = {20000,12288,192,4096,64,64,64,64,64,4096,64,24576,128,8192,64,
                        8192,64,4096,64,64,64,16384,256,16384,64,64,64};
  int f32 = sniff_f32(tng);
  int i = blockIdx.x*256 + threadIdx.x;
  if (i >= W_TOT) return;
  int seg = 0, off = i;
  while (off >= wseg[seg]) { off -= wseg[seg]; ++seg; }
  const void* p = wp_in.p[seg];
  out[i] = f32 ? f2bf(((const float*)p)[off]) : ((const bf16*)p)[off];
}

// ---------------- pre-swizzle: inw/ow into B-frag + wd/wb (m_w1 halves) -----
// frag el: [((ks*CT+ct)*64+lane)*8+j] = W[32ks+quad*8+j][16ct+l15]
__global__ __launch_bounds__(256) void k_swz_pre(const bf16* __restrict__ wp,
                                                 bf16* __restrict__ sp){
  int i = blockIdx.x*256 + threadIdx.x;   // 32768
  int base, CT, N, woff, mode = 0;
  if      (i < 12288) { base=0;     CT=12; N=192; woff=W_INW; }
  else if (i < 16384) { base=12288; CT=4;  N=64;  woff=W_OW;  }
  else if (i < 24576) { base=16384; CT=8;  N=128; woff=W_MW1; mode=1; } // Wa-Wb
  else                { base=24576; CT=8;  N=128; woff=W_MW1 + 64*128; } // Wb
  int loc = i - base;
  int j = loc & 7, lane = (loc >> 3) & 63, fi = loc >> 9;
  int ct = fi % CT, ks = fi / CT;
  int k = 32*ks + (lane >> 4)*8 + j;
  int nn = 16*ct + (lane & 15);
  if (mode) sp[i] = f2bf(bf2f(wp[W_MW1 + k*128 + nn]) - bf2f(wp[W_MW1 + (64+k)*128 + nn]));
  else      sp[i] = wp[woff + k*N + nn];
}

// ---------------- Stage 1: attention + LN, MFMA projections -----------------
__global__ __launch_bounds__(256) void k_attn(
    const bf16* __restrict__ xn, const bf16* __restrict__ wp,
    const bf16* __restrict__ swzpre, bf16* __restrict__ buf1)
{
  __shared__ __align__(16) short xt16[16][72];
  __shared__ float qq[16][64];
  __shared__ float kk[16][64];
  __shared__ float vsm[16][64];
  __shared__ __align__(16) short aot[16][72];
  __shared__ float res[16][64];
  __shared__ float mu[16], rs[16];
  int t = threadIdx.x;
  int w = t >> 6, lane = t & 63, quad = lane >> 4, l15 = lane & 15;
  int b = blockIdx.x / Nn, n = blockIdx.x - b*Nn;
  for (int i = t; i < 512; i += 256) {    // 16 rows x 32 uints
    int s = i >> 5, cu = i & 31;
    *(unsigned*)&xt16[s][2*cu] = ((const unsigned*)xn)[((size_t)(b*Ss+s)*Nn + n)*32 + cu];
  }
  __syncthreads();
  // qkv MFMA: M=16,K=64,N=192 (12 col-tiles; wave w -> 3w..3w+2)
  bfrag a[2];
  #pragma unroll
  for (int ks = 0; ks < 2; ++ks)
    a[ks] = *(const bfrag*)&xt16[l15][32*ks + quad*8];
  const bfrag* SQKV = (const bfrag*)swzpre;
  #pragma unroll
  for (int ci = 0; ci < 3; ++ci) {
    int ct = 3*w + ci;
    f32x4 acc = {0.f,0.f,0.f,0.f};
    #pragma unroll
    for (int ks = 0; ks < 2; ++ks)
      acc = __builtin_amdgcn_mfma_f32_16x16x32_bf16(a[ks], SQKV[(ks*12+ct)*64 + lane], acc, 0,0,0);
    int c = ct*16 + l15;
    float bias = bf2f(wp[W_INB + c]);
    float* dst = (c < 64) ? &qq[0][0] : (c < 128) ? &kk[0][0] : &vsm[0][0];
    int cc = c & 63;
    #pragma unroll
    for (int r = 0; r < 4; ++r)
      dst[(quad*4 + r)*64 + cc] = acc[r] + bias;
  }
  __syncthreads();
  // attention (wave 0 only; S=16, hd=16, scale 0.25)
  if (t < 64) {
    int hd = t >> 4, sq = t & 15;
    float sc[16]; float mx = -3.0e38f;
    #pragma unroll
    for (int sk = 0; sk < 16; ++sk) {
      float s1 = 0.f;
      #pragma unroll
      for (int d = 0; d < 16; ++d) s1 += qq[sq][hd*16+d]*kk[sk][hd*16+d];
      s1 *= 0.25f;
      sc[sk] = s1; mx = fmaxf(mx, s1);
    }
    float ssum = 0.f;
    #pragma unroll
    for (int sk = 0; sk < 16; ++sk) { sc[sk] = expf(sc[sk]-mx); ssum += sc[sk]; }
    float inv = 1.0f/ssum;
    #pragma unroll
    for (int d = 0; d < 16; ++d) {
      float s1 = 0.f;
      #pragma unroll
      for (int sk = 0; sk < 16; ++sk) s1 += sc[sk]*vsm[sk][hd*16+d];
      *(bf16*)&aot[sq][hd*16+d] = f2bf(s1*inv);
    }
  }
  __syncthreads();
  // out_proj MFMA: M=16,K=64,N=64 (wave w -> col-tile w) + bias + residual
  bfrag af[2];
  #pragma unroll
  for (int ks = 0; ks < 2; ++ks)
    af[ks] = *(const bfrag*)&aot[l15][32*ks + quad*8];
  const bfrag* SOW = (const bfrag*)(swzpre + 12288);
  {
    f32x4 acc = {0.f,0.f,0.f,0.f};
    #pragma unroll
    for (int ks = 0; ks < 2; ++ks)
      acc = __builtin_amdgcn_mfma_f32_16x16x32_bf16(af[ks], SOW[(ks*4+w)*64 + lane], acc, 0,0,0);
    int c = w*16 + l15;
    float bias = bf2f(wp[W_OB + c]);
    #pragma unroll
    for (int r = 0; r < 4; ++r)
      res[quad*4 + r][c] = acc[r] + bias + bf2f(*(const bf16*)&xt16[quad*4 + r][c]);
  }
  __syncthreads();
  if (t < 16) {
    float m = 0.f;
    for (int h = 0; h < 64; ++h) m += res[t][h];
    m *= (1.0f/64.0f);
    float v2 = 0.f;
    for (int h = 0; h < 64; ++h) { float d = res[t][h]-m; v2 += d*d; }
    mu[t] = m; rs[t] = rsqrtf(v2*(1.0f/64.0f) + 1e-5f);
  }
  __syncthreads();
  for (int i = t; i < 1024; i += 256) {
    int s = i >> 6, j = i & 63;
    float o = (res[s][j]-mu[s])*rs[s]*bf2f(wp[W_TNG + j]) + bf2f(wp[W_TNB + j]);
    buf1[(((size_t)(b*Ss+s))*Nn + n)*64 + j] = f2bf(o);
  }
}

// ---------------- Stage 2b: P = xs@(Wa-Wb) and Q = xs@Wb (MFMA) -------------
__global__ __launch_bounds__(256) void k_p2(
    const bf16* __restrict__ buf1, const bf16* __restrict__ swzwd,
    const bf16* __restrict__ swzwb, bf16* __restrict__ P,
    bf16* __restrict__ QA, int writeQ)
{
  __shared__ __align__(16) short xst[64][72];
  int t = threadIdx.x;
  int w = t >> 6, lane = t & 63, quad = lane >> 4, l15 = lane & 15;
  size_t rowbase = (size_t)blockIdx.x * 64;
  const unsigned* bx = (const unsigned*)(buf1 + rowbase*64);
  for (int i = t; i < 2048; i += 256) {
    int r = i >> 5, cu = i & 31;
    *(unsigned*)&xst[r][2*cu] = bx[i];
  }
  __syncthreads();
  int row0 = w*16;
  bfrag a[2];
  #pragma unroll
  for (int ks = 0; ks < 2; ++ks)
    a[ks] = *(const bfrag*)&xst[row0 + l15][32*ks + quad*8];
  const bfrag* SWD = (const bfrag*)swzwd;
  #pragma unroll
  for (int ct = 0; ct < 8; ++ct) {
    f32x4 acc = {0.f,0.f,0.f,0.f};
    #pragma unroll
    for (int ks = 0; ks < 2; ++ks)
      acc = __builtin_amdgcn_mfma_f32_16x16x32_bf16(a[ks], SWD[(ks*8+ct)*64 + lane], acc, 0,0,0);
    #pragma unroll
    for (int r = 0; r < 4; ++r)
      P[(rowbase + row0 + quad*4 + r)*128 + ct*16 + l15] = f2bf(acc[r]);
  }
  if (writeQ) {
    const bfrag* SWB = (const bfrag*)swzwb;
    #pragma unroll
    for (int ct = 0; ct < 8; ++ct) {
      f32x4 acc = {0.f,0.f,0.f,0.f};
      #pragma unroll
      for (int ks = 0; ks < 2; ++ks)
        acc = __builtin_amdgcn_mfma_f32_16x16x32_bf16(a[ks], SWB[(ks*8+ct)*64 + lane], acc, 0,0,0);
      #pragma unroll
      for (int r = 0; r < 4; ++r)
        QA[(rowbase + row0 + quad*4 + r)*128 + ct*16 + l15] = f2bf(acc[r]);
    }
  }
}

// ---------------- Stage 2a: edge embedding -> c_e = m_b1 + edge_emb @ Wc ----
__global__ __launch_bounds__(128) void k_edge(
    const bf16* __restrict__ wp, bf16* __restrict__ c_e)
{
  int e = blockIdx.x;
  __shared__ float tmp[64], emb[64];
  int t = threadIdx.x;
  float a = bf2f(wp[W_EA + e]);
  if (t < 64) tmp[t] = gelu_f(a*bf2f(wp[W_EW1 + t]) + bf2f(wp[W_EB1 + t]));
  __syncthreads();
  if (t < 64) {
    float acc = bf2f(wp[W_EB2 + t]);
    for (int h = 0; h < 64; ++h) acc += tmp[h]*bf2f(wp[W_EW2 + h*64 + t]);
    emb[t] = acc;
  }
  __syncthreads();
  float acc = bf2f(wp[W_MB1 + t]);
  for (int h = 0; h < 64; ++h) acc += emb[h]*bf2f(wp[W_MW1 + (128+h)*128 + t]);
  c_e[(size_t)e*128 + t] = f2bf(acc);
}

// ---------------- CSR build ------------------------------------------------
__global__ void k_deg(const int* __restrict__ ei, int* __restrict__ deg){
  int e = blockIdx.x*256 + threadIdx.x;
  if (e < Ee) atomicAdd(&deg[ei[Ee + e]], 1);
}

__global__ __launch_bounds__(256) void k_scan(const int* __restrict__ deg, int* __restrict__ row_st){
  __shared__ int part[256];
  int t = threadIdx.x;
  int base = t*20;
  int s = 0;
  for (int i = 0; i < 20; ++i) { int idx = base+i; if (idx < Nn) s += deg[idx]; }
  part[t] = s;
  __syncthreads();
  for (int off = 1; off < 256; off <<= 1) {
    int v = (t >= off) ? part[t-off] : 0;
    __syncthreads();
    part[t] += v;
    __syncthreads();
  }
  int run = (t == 0) ? 0 : part[t-1];
  for (int i = 0; i < 20; ++i) {
    int idx = base + i;
    if (idx < Nn) { row_st[idx] = run; run += deg[idx]; }
    else if (idx == Nn) { row_st[Nn] = run; }
  }
}

__global__ void k_fill(const int* __restrict__ ei, const int* __restrict__ row_st,
                       int* __restrict__ cursor, int* __restrict__ sorted){
  int e = blockIdx.x*256 + threadIdx.x;
  if (e >= Ee) return;
  int d = ei[Ee + e];
  int pos = atomicAdd(&cursor[d], 1);
  sorted[row_st[d] + pos] = e;
}

// ---------------- Stage 2c (big): edge loop only; QA row: read Q, write hsum -
// One wave per segment; each row of QA is read then overwritten by its own
// wave only (no cross-row access) -> Q and hsum share the buffer.
__global__ __launch_bounds__(256) void k_gather_q(
    const int* __restrict__ ei, const int* __restrict__ row_st, const int* __restrict__ sorted,
    const bf16* __restrict__ c_e, const bf16* __restrict__ P, bf16* __restrict__ QA)
{
  int t = threadIdx.x;
  int w = t >> 6, lane = t & 63;
  int sid = blockIdx.x*4 + w;
  int bs = sid / Nn, n = sid - bs*Nn;
  size_t rowoff = (size_t)(bs*Nn + n);
  unsigned qv = ((const unsigned*)QA)[rowoff*64 + lane];
  float q0 = bfu((unsigned short)qv), q1 = bfu((unsigned short)(qv >> 16));
  const unsigned* Pb = (const unsigned*)P + (size_t)bs*Nn*64;
  const unsigned* Cb = (const unsigned*)c_e;
  int s0 = row_st[n], s1 = row_st[n+1];
  float a0 = 0.f, a1 = 0.f;
  for (int ii = s0; ii < s1; ++ii) {
    int e = sorted[ii];
    int src = ei[e];
    unsigned pv = Pb[(size_t)src*64 + lane];
    unsigned cv = Cb[(size_t)e*64 + lane];
    a0 += gelu_f(bfu((unsigned short)pv)         + q0 + bfu((unsigned short)cv));
    a1 += gelu_f(bfu((unsigned short)(pv >> 16)) + q1 + bfu((unsigned short)(cv >> 16)));
  }
  ((unsigned*)QA)[rowoff*64 + lane] = pack2(a0, a1);
}

// ---------------- fold: Wfold = mw2 @ uw1_bot (swz-layout) + mbu -------------
__global__ __launch_bounds__(256) void k_fold(const bf16* __restrict__ wp,
                                              bf16* __restrict__ swz2, float* __restrict__ mbu){
  int gid = blockIdx.x*256 + threadIdx.x;   // 8192
  int k = gid >> 6, c = gid & 63;
  float acc = 0.f;
  for (int j = 0; j < 64; ++j)
    acc += bf2f(wp[W_MW2 + k*64 + j]) * bf2f(wp[W_UW1 + (64+j)*64 + c]);
  int ks = k >> 5, r5 = k & 31, quad = r5 >> 3, j8 = r5 & 7;
  int ct = c >> 4, l15 = c & 15, lane = quad*16 + l15;
  swz2[4096 + ((ks*4+ct)*64 + lane)*8 + j8] = f2bf(acc);
  if (gid < 64) {
    float m = 0.f;
    for (int j = 0; j < 64; ++j)
      m += bf2f(wp[W_MB2 + j]) * bf2f(wp[W_UW1 + (64+j)*64 + gid]);
    mbu[gid] = m;
  }
}

// ---------------- swizzle uw1_top/uw2/fw1/fw2 (big path) --------------------
__global__ __launch_bounds__(256) void k_swz2(const bf16* __restrict__ wp,
                                              bf16* __restrict__ swz2){
  int i = blockIdx.x*256 + threadIdx.x;   // 49152
  if (i >= 49152) return;
  if (i >= 4096 && i < 12288) return;     // Wfold region (k_fold writes it)
  int base, CT, N, woff;
  if      (i < 4096)  { base=0;     CT=4;  N=64;  woff=W_UW1; }   // rows 0..63
  else if (i < 16384) { base=12288; CT=4;  N=64;  woff=W_UW2; }
  else if (i < 32768) { base=16384; CT=16; N=256; woff=W_FW1; }
  else                { base=32768; CT=4;  N=64;  woff=W_FW2; }
  int loc = i - base;
  int j = loc & 7, lane = (loc >> 3) & 63, fi = loc >> 9;
  int ct = fi % CT, ks = fi / CT;
  int k = 32*ks + (lane >> 4)*8 + j;
  int nn = 16*ct + (lane & 15);
  swz2[i] = wp[woff + k*N + nn];
}

// ---------------- Stage 2d+3 (big): folded update MLP + LN2 + FFN + LN3 -----
__global__ __launch_bounds__(256) void k_upd2(
    const bf16* __restrict__ buf1, const bf16* __restrict__ QA,
    const bf16* __restrict__ swz2, const bf16* __restrict__ wp,
    const float* __restrict__ mbu, const int* __restrict__ row_st,
    const void* __restrict__ tng_raw, void* __restrict__ outv)
{
  __shared__ __align__(16) short updt[64][136];  // 0..63 xs->xs2, 64..127 h2
  __shared__ __align__(16) short mid[64][264];   // hsum (128) then FFN hidden (256)
  __shared__ float degs[64];
  int t = threadIdx.x;
  int w = t >> 6, lane = t & 63, quad = lane >> 4, l15 = lane & 15;
  int f32o = sniff_f32(tng_raw);
  size_t rowbase = (size_t)blockIdx.x * 64;
  const unsigned* bx = (const unsigned*)(buf1 + rowbase*64);
  const unsigned* qa = (const unsigned*)(QA + rowbase*128);
  for (int i = t; i < 2048; i += 256) {
    int r = i >> 5, cu = i & 31;
    *(unsigned*)&updt[r][2*cu] = bx[i];
  }
  for (int i = t; i < 4096; i += 256) {
    int r = i >> 6, cu = i & 63;
    *(unsigned*)&mid[r][2*cu] = qa[i];
  }
  if (t < 64) {
    int n = (int)((rowbase + t) % Nn);
    degs[t] = (float)(row_st[n+1] - row_st[n]);
  }
  __syncthreads();
  int row0 = w*16;

  // ---- GEMM2: h2 = gelu(xs@uw1_top + hsum@Wfold + deg*mbu + ub1) ----
  bfrag a2x[2], a2h[4];
  #pragma unroll
  for (int ks = 0; ks < 2; ++ks)
    a2x[ks] = *(const bfrag*)&updt[row0 + l15][32*ks + quad*8];
  #pragma unroll
  for (int ks = 0; ks < 4; ++ks)
    a2h[ks] = *(const bfrag*)&mid[row0 + l15][32*ks + quad*8];
  const bfrag* SU1 = (const bfrag*)swz2;
  const bfrag* SWF = (const bfrag*)(swz2 + 4096);
  #pragma unroll
  for (int ct = 0; ct < 4; ++ct) {
    f32x4 acc = {0.f,0.f,0.f,0.f};
    #pragma unroll
    for (int ks = 0; ks < 2; ++ks)
      acc = __builtin_amdgcn_mfma_f32_16x16x32_bf16(a2x[ks], SU1[(ks*4+ct)*64 + lane], acc, 0,0,0);
    #pragma unroll
    for (int ks = 0; ks < 4; ++ks)
      acc = __builtin_amdgcn_mfma_f32_16x16x32_bf16(a2h[ks], SWF[(ks*4+ct)*64 + lane], acc, 0,0,0);
    int col = ct*16 + l15;
    float b1 = bf2f(wp[W_UB1 + col]);
    float mb = mbu[col];
    #pragma unroll
    for (int r = 0; r < 4; ++r) {
      int row = row0 + quad*4 + r;
      *(bf16*)&updt[row][64 + col] = f2bf(gelu_f(acc[r] + b1 + degs[row]*mb));
    }
  }
  __syncthreads();

  // ---- GEMM3: xs2 = LN2(xs + h2 @ uw2 + ub2) ----
  bfrag a3[2];
  #pragma unroll
  for (int ks = 0; ks < 2; ++ks)
    a3[ks] = *(const bfrag*)&updt[row0 + l15][64 + 32*ks + quad*8];
  const bfrag* SU2 = (const bfrag*)(swz2 + 12288);
  float xv[4][4];
  #pragma unroll
  for (int ct = 0; ct < 4; ++ct) {
    f32x4 acc = {0.f,0.f,0.f,0.f};
    #pragma unroll
    for (int ks = 0; ks < 2; ++ks)
      acc = __builtin_amdgcn_mfma_f32_16x16x32_bf16(a3[ks], SU2[(ks*4+ct)*64 + lane], acc, 0,0,0);
    float b2 = bf2f(wp[W_UB2 + ct*16 + l15]);
    #pragma unroll
    for (int r = 0; r < 4; ++r)
      xv[ct][r] = acc[r] + b2 + bf2f(*(const bf16*)&updt[row0 + quad*4 + r][ct*16 + l15]);
  }
  {
    float g[4], bb[4];
    #pragma unroll
    for (int ct = 0; ct < 4; ++ct) { g[ct] = bf2f(wp[W_SNG + ct*16 + l15]); bb[ct] = bf2f(wp[W_SNB + ct*16 + l15]); }
    #pragma unroll
    for (int r = 0; r < 4; ++r) {
      float part = xv[0][r] + xv[1][r] + xv[2][r] + xv[3][r];
      part += __shfl_xor(part, 1, 64); part += __shfl_xor(part, 2, 64);
      part += __shfl_xor(part, 4, 64); part += __shfl_xor(part, 8, 64);
      float mean = part*(1.0f/64.0f);
      float p2 = 0.f;
      #pragma unroll
      for (int ct = 0; ct < 4; ++ct) { float d = xv[ct][r]-mean; p2 += d*d; }
      p2 += __shfl_xor(p2, 1, 64); p2 += __shfl_xor(p2, 2, 64);
      p2 += __shfl_xor(p2, 4, 64); p2 += __shfl_xor(p2, 8, 64);
      float rstd = rsqrtf(p2*(1.0f/64.0f) + 1e-5f);
      #pragma unroll
      for (int ct = 0; ct < 4; ++ct) {
        float xs2 = (xv[ct][r]-mean)*rstd*g[ct] + bb[ct];
        *(bf16*)&updt[row0 + quad*4 + r][ct*16 + l15] = f2bf(xs2);
      }
    }
  }
  __syncthreads();

  // ---- GEMM4: mid = gelu(xs2 @ fw1 + fb1) ----
  bfrag a4[2];
  #pragma unroll
  for (int ks = 0; ks < 2; ++ks)
    a4[ks] = *(const bfrag*)&updt[row0 + l15][32*ks + quad*8];
  const bfrag* SF1 = (const bfrag*)(swz2 + 16384);
  #pragma unroll
  for (int ct = 0; ct < 16; ++ct) {
    f32x4 acc = {0.f,0.f,0.f,0.f};
    #pragma unroll
    for (int ks = 0; ks < 2; ++ks)
      acc = __builtin_amdgcn_mfma_f32_16x16x32_bf16(a4[ks], SF1[(ks*16+ct)*64 + lane], acc, 0,0,0);
    float b = bf2f(wp[W_FB1 + ct*16 + l15]);
    #pragma unroll
    for (int r = 0; r < 4; ++r)
      *(bf16*)&mid[row0 + quad*4 + r][ct*16 + l15] = f2bf(gelu_f(acc[r] + b));
  }
  __syncthreads();

  // ---- GEMM5: out = LN3(xs2 + mid @ fw2 + fb2) ----
  bfrag a5[8];
  #pragma unroll
  for (int ks = 0; ks < 8; ++ks)
    a5[ks] = *(const bfrag*)&mid[row0 + l15][32*ks + quad*8];
  const bfrag* SF2 = (const bfrag*)(swz2 + 32768);
  float ov[4][4];
  #pragma unroll
  for (int ct = 0; ct < 4; ++ct) {
    f32x4 acc = {0.f,0.f,0.f,0.f};
    #pragma unroll
    for (int ks = 0; ks < 8; ++ks)
      acc = __builtin_amdgcn_mfma_f32_16x16x32_bf16(a5[ks], SF2[(ks*4+ct)*64 + lane], acc, 0,0,0);
    float b = bf2f(wp[W_FB2 + ct*16 + l15]);
    #pragma unroll
    for (int r = 0; r < 4; ++r)
      ov[ct][r] = acc[r] + b + bf2f(*(const bf16*)&updt[row0 + quad*4 + r][ct*16 + l15]);
  }
  {
    float g[4], bb[4];
    #pragma unroll
    for (int ct = 0; ct < 4; ++ct) { g[ct] = bf2f(wp[W_FNG + ct*16 + l15]); bb[ct] = bf2f(wp[W_FNB + ct*16 + l15]); }
    #pragma unroll
    for (int r = 0; r < 4; ++r) {
      float part = ov[0][r] + ov[1][r] + ov[2][r] + ov[3][r];
      part += __shfl_xor(part, 1, 64); part += __shfl_xor(part, 2, 64);
      part += __shfl_xor(part, 4, 64); part += __shfl_xor(part, 8, 64);
      float mean = part*(1.0f/64.0f);
      float p2 = 0.f;
      #pragma unroll
      for (int ct = 0; ct < 4; ++ct) { float d = ov[ct][r]-mean; p2 += d*d; }
      p2 += __shfl_xor(p2, 1, 64); p2 += __shfl_xor(p2, 2, 64);
      p2 += __shfl_xor(p2, 4, 64); p2 += __shfl_xor(p2, 8, 64);
      float rstd = rsqrtf(p2*(1.0f/64.0f) + 1e-5f);
      size_t rowg = rowbase + row0 + quad*4 + r;
      #pragma unroll
      for (int ct = 0; ct < 4; ++ct) {
        float o = (ov[ct][r]-mean)*rstd*g[ct] + bb[ct];
        size_t idx = rowg*64 + ct*16 + l15;
        if (f32o) ((float*)outv)[idx] = o;
        else      ((bf16*)outv)[idx] = f2bf(o);
      }
    }
  }
}

// =================== FALLBACK PATH (proven R7 kernels) ======================
__global__ __launch_bounds__(256) void k_swz_upd(const bf16* __restrict__ wp,
                                                 bf16* __restrict__ swz){
  int i = blockIdx.x*256 + threadIdx.x;   // 45056
  if (i >= 45056) return;
  int base, CT, N, woff;
  if      (i < 8192)  { base=0;     CT=4;  N=64;  woff=W_UW1; }
  else if (i < 12288) { base=8192;  CT=4;  N=64;  woff=W_UW2; }
  else if (i < 28672) { base=12288; CT=16; N=256; woff=W_FW1; }
  else                { base=28672; CT=4;  N=64;  woff=W_FW2; }
  int loc = i - base;
  int j = loc & 7, lane = (loc >> 3) & 63, fi = loc >> 9;
  int ct = fi % CT, ks = fi / CT;
  int k = 32*ks + (lane >> 4)*8 + j;
  int nn = 16*ct + (lane & 15);
  swz[i] = wp[woff + k*N + nn];
}

__global__ __launch_bounds__(256) void k_gather(
    const int* __restrict__ ei, const int* __restrict__ row_st, const int* __restrict__ sorted,
    const bf16* __restrict__ c_e, const bf16* __restrict__ wp,
    const bf16* __restrict__ buf1, const bf16* __restrict__ P, bf16* __restrict__ aggrbuf)
{
  __shared__ unsigned wbl2[64][64];
  __shared__ float hsum[4][128];
  int t = threadIdx.x;
  int w = t >> 6, lane = t & 63;
  for (int i = t; i < 64*64; i += 256) {
    int h = i >> 6, l = i & 63;
    wbl2[h][l] = ((const unsigned*)(wp + W_MW1 + (64+h)*128))[l];
  }
  int sid = blockIdx.x*4 + w;
  int bs = sid / Nn, n = sid - bs*Nn;
  size_t rowoff = (size_t)(bs*Nn + n);
  float xi = bf2f(buf1[rowoff*64 + lane]);
  __syncthreads();
  float q0 = 0.f, q1 = 0.f;
  #pragma unroll
  for (int h = 0; h < 64; ++h) {
    float xv = rl(xi, h);
    unsigned wpair = wbl2[h][lane];
    q0 += xv*bfu((unsigned short)wpair);
    q1 += xv*bfu((unsigned short)(wpair >> 16));
  }
  const unsigned* Pb = (const unsigned*)P + (size_t)bs*Nn*64;
  const unsigned* Cb = (const unsigned*)c_e;
  int s0 = row_st[n], s1 = row_st[n+1];
  float a0 = 0.f, a1 = 0.f;
  for (int ii = s0; ii < s1; ++ii) {
    int e = sorted[ii];
    int src = ei[e];
    unsigned pv = Pb[(size_t)src*64 + lane];
    unsigned cv = Cb[(size_t)e*64 + lane];
    a0 += gelu_f(bfu((unsigned short)pv)         + q0 + bfu((unsigned short)cv));
    a1 += gelu_f(bfu((unsigned short)(pv >> 16)) + q1 + bfu((unsigned short)(cv >> 16)));
  }
  ((float2*)hsum[w])[lane] = make_float2(a0, a1);
  __syncthreads();
  float deg_f = (float)(s1 - s0);
  float aggr = deg_f * bf2f(wp[W_MB2 + lane]);
  for (int k = 0; k < 128; ++k) aggr += hsum[w][k]*bf2f(wp[W_MW2 + k*64 + lane]);
  aggrbuf[rowoff*64 + lane] = f2bf(aggr);
}

__global__ __launch_bounds__(256) void k_upd(
    const bf16* __restrict__ buf1, const bf16* __restrict__ aggrbuf,
    const bf16* __restrict__ swz, const bf16* __restrict__ wp,
    const void* __restrict__ tng_raw, void* __restrict__ outv)
{
  __shared__ __align__(16) short updt[64][136];
  __shared__ __align__(16) short mid[64][264];
  int t = threadIdx.x;
  int w = t >> 6, lane = t & 63, quad = lane >> 4, l15 = lane & 15;
  int f32o = sniff_f32(tng_raw);
  size_t rowbase = (size_t)blockIdx.x * 64;
  const unsigned* bx = (const unsigned*)(buf1 + rowbase*64);
  const unsigned* ba = (const unsigned*)(aggrbuf + rowbase*64);
  for (int i = t; i < 2048; i += 256) {
    int r = i >> 5, cu = i & 31;
    *(unsigned*)&updt[r][2*cu]      = bx[i];
    *(unsigned*)&updt[r][64 + 2*cu] = ba[i];
  }
  __syncthreads();
  int row0 = w*16;
  const bfrag* SW = (const bfrag*)swz;

  bfrag a2[4];
  #pragma unroll
  for (int ks = 0; ks < 4; ++ks)
    a2[ks] = *(const bfrag*)&updt[row0 + l15][32*ks + quad*8];
  float h2v[4][4];
  #pragma unroll
  for (int ct = 0; ct < 4; ++ct) {
    f32x4 acc = {0.f,0.f,0.f,0.f};
    #pragma unroll
    for (int ks = 0; ks < 4; ++ks)
      acc = __builtin_amdgcn_mfma_f32_16x16x32_bf16(a2[ks], SW[(ks*4+ct)*64 + lane], acc, 0,0,0);
    float b1 = bf2f(wp[W_UB1 + ct*16 + l15]);
    #pragma unroll
    for (int r = 0; r < 4; ++r) h2v[ct][r] = gelu_f(acc[r] + b1);
  }
  #pragma unroll
  for (int ct = 0; ct < 4; ++ct)
    #pragma unroll
    for (int r = 0; r < 4; ++r)
      *(bf16*)&updt[row0 + quad*4 + r][64 + ct*16 + l15] = f2bf(h2v[ct][r]);
  __syncthreads();

  bfrag a3[2];
  #pragma unroll
  for (int ks = 0; ks < 2; ++ks)
    a3[ks] = *(const bfrag*)&updt[row0 + l15][64 + 32*ks + quad*8];
  float xv[4][4];
  #pragma unroll
  for (int ct = 0; ct < 4; ++ct) {
    f32x4 acc = {0.f,0.f,0.f,0.f};
    #pragma unroll
    for (int ks = 0; ks < 2; ++ks)
      acc = __builtin_amdgcn_mfma_f32_16x16x32_bf16(a3[ks], SW[1024 + (ks*4+ct)*64 + lane], acc, 0,0,0);
    float b2 = bf2f(wp[W_UB2 + ct*16 + l15]);
    #pragma unroll
    for (int r = 0; r < 4; ++r)
      xv[ct][r] = acc[r] + b2 + bf2f(*(const bf16*)&updt[row0 + quad*4 + r][ct*16 + l15]);
  }
  {
    float g[4], bb[4];
    #pragma unroll
    for (int ct = 0; ct < 4; ++ct) { g[ct] = bf2f(wp[W_SNG + ct*16 + l15]); bb[ct] = bf2f(wp[W_SNB + ct*16 + l15]); }
    #pragma unroll
    for (int r = 0; r < 4; ++r) {
      float part = xv[0][r] + xv[1][r] + xv[2][r] + xv[3][r];
      part += __shfl_xor(part, 1, 64); part += __shfl_xor(part, 2, 64);
      part += __shfl_xor(part, 4, 64); part += __shfl_xor(part, 8, 64);
      float mean = part*(1.0f/64.0f);
      float p2 = 0.f;
      #pragma unroll
      for (int ct = 0; ct < 4; ++ct) { float d = xv[ct][r]-mean; p2 += d*d; }
      p2 += __shfl_xor(p2, 1, 64); p2 += __shfl_xor(p2, 2, 64);
      p2 += __shfl_xor(p2, 4, 64); p2 += __shfl_xor(p2, 8, 64);
      float rstd = rsqrtf(p2*(1.0f/64.0f) + 1e-5f);
      #pragma unroll
      for (int ct = 0; ct < 4; ++ct) {
        float xs2 = (xv[ct][r]-mean)*rstd*g[ct] + bb[ct];
        *(bf16*)&updt[row0 + quad*4 + r][ct*16 + l15] = f2bf(xs2);
      }
    }
  }
  __syncthreads();

  bfrag a4[2];
  #pragma unroll
  for (int ks = 0; ks < 2; ++ks)
    a4[ks] = *(const bfrag*)&updt[row0 + l15][32*ks + quad*8];
  #pragma unroll
  for (int ct = 0; ct < 16; ++ct) {
    f32x4 acc = {0.f,0.f,0.f,0.f};
    #pragma unroll
    for (int ks = 0; ks < 2; ++ks)
      acc = __builtin_amdgcn_mfma_f32_16x16x32_bf16(a4[ks], SW[1536 + (ks*16+ct)*64 + lane], acc, 0,0,0);
    float b = bf2f(wp[W_FB1 + ct*16 + l15]);
    #pragma unroll
    for (int r = 0; r < 4; ++r)
      *(bf16*)&mid[row0 + quad*4 + r][ct*16 + l15] = f2bf(gelu_f(acc[r] + b));
  }
  __syncthreads();

  bfrag a5[8];
  #pragma unroll
  for (int ks = 0; ks < 8; ++ks)
    a5[ks] = *(const bfrag*)&mid[row0 + l15][32*ks + quad*8];
  float ov[4][4];
  #pragma unroll
  for (int ct = 0; ct < 4; ++ct) {
    f32x4 acc = {0.f,0.f,0.f,0.f};
    #pragma unroll
    for (int ks = 0; ks < 8; ++ks)
      acc = __builtin_amdgcn_mfma_f32_16x16x32_bf16(a5[ks], SW[3584 + (ks*4+ct)*64 + lane], acc, 0,0,0);
    float b = bf2f(wp[W_FB2 + ct*16 + l15]);
    #pragma unroll
    for (int r = 0; r < 4; ++r)
      ov[ct][r] = acc[r] + b + bf2f(*(const bf16*)&updt[row0 + quad*4 + r][ct*16 + l15]);
  }
  {
    float g[4], bb[4];
    #pragma unroll
    for (int ct = 0; ct < 4; ++ct) { g[ct] = bf2f(wp[W_FNG + ct*16 + l15]); bb[ct] = bf2f(wp[W_FNB + ct*16 + l15]); }
    #pragma unroll
    for (int r = 0; r < 4; ++r) {
      float part = ov[0][r] + ov[1][r] + ov[2][r] + ov[3][r];
      part += __shfl_xor(part, 1, 64); part += __shfl_xor(part, 2, 64);
      part += __shfl_xor(part, 4, 64); part += __shfl_xor(part, 8, 64);
      float mean = part*(1.0f/64.0f);
      float p2 = 0.f;
      #pragma unroll
      for (int ct = 0; ct < 4; ++ct) { float d = ov[ct][r]-mean; p2 += d*d; }
      p2 += __shfl_xor(p2, 1, 64); p2 += __shfl_xor(p2, 2, 64);
      p2 += __shfl_xor(p2, 4, 64); p2 += __shfl_xor(p2, 8, 64);
      float rstd = rsqrtf(p2*(1.0f/64.0f) + 1e-5f);
      size_t rowg = rowbase + row0 + quad*4 + r;
      #pragma unroll
      for (int ct = 0; ct < 4; ++ct) {
        float o = (ov[ct][r]-mean)*rstd*g[ct] + bb[ct];
        size_t idx = rowg*64 + ct*16 + l15;
        if (f32o) ((float*)outv)[idx] = o;
        else      ((bf16*)outv)[idx] = f2bf(o);
      }
    }
  }
}

extern "C" void kernel_launch(void* const* d_in, const int* in_sizes, int n_in,
                              void* d_out, int out_size, void* d_ws, size_t ws_size,
                              hipStream_t stream)
{
  const void* x   = d_in[0];
  const int*  ei  = (const int*)d_in[1];
  const void* tng = d_in[7];

  char* w = (char*)d_ws;
  bf16* xnorm  = (bf16*)(w);                   // 20,480,000 (dead after k_attn)
  bf16* buf1   = (bf16*)(w + 20480000);        // 20,480,000 (LN1 out)
  bf16* cebuf  = (bf16*)(w + 40960000);        //  5,120,000 (swzpre -> c_e -> swz2)
  bf16* wpack  = (bf16*)(w + 46080000);        //    239,552
  int* deg     = (int*) (w + 46320128);
  int* row_st  = (int*) (w + 46340160);
  int* cursor  = (int*) (w + 46360192);
  int* sorted  = (int*) (w + 46380224);        // end 46,460,224
  float* mbu   = (float*)(w + 46460416);       // 256 B

  bool big = ws_size >= (size_t)128384000;
  bf16* P  = (ws_size >= (size_t)87424000) ? (bf16*)(w + 46464000) : (bf16*)d_out;
  bf16* QA = (bf16*)(w + 87424000);            // big path only: Q then hsum
  bf16* aggrb = xnorm;                         // fallback gather output
  bf16* swzpre = cebuf;                        // 32768 els, alive swz_pre..k_p2

  WPtrs wps;
  for (int i = 0; i < 27; ++i) wps.p[i] = d_in[2 + i];

  hipMemsetAsync(deg,    0, Nn*sizeof(int), stream);
  hipMemsetAsync(cursor, 0, Nn*sizeof(int), stream);

  k_norm_x<<<XN/256, 256, 0, stream>>>(x, tng, xnorm);
  k_norm_w<<<(W_TOT+255)/256, 256, 0, stream>>>(wps, tng, wpack);
  k_swz_pre<<<128, 256, 0, stream>>>(wpack, swzpre);
  k_attn<<<Bb*Nn, 256, 0, stream>>>(xnorm, wpack, swzpre, buf1);
  k_p2<<<ROWS/64, 256, 0, stream>>>(buf1, swzpre + 16384, swzpre + 24576,
                                    P, big ? QA : P, big ? 1 : 0);
  k_edge<<<Ee, 128, 0, stream>>>(wpack, cebuf);   // overwrites swzpre (done)
  k_deg <<<(Ee+255)/256, 256, 0, stream>>>(ei, deg);
  k_scan<<<1, 256, 0, stream>>>(deg, row_st);
  k_fill<<<(Ee+255)/256, 256, 0, stream>>>(ei, row_st, cursor, sorted);
  if (big) {
    k_gather_q<<<ROWS/4, 256, 0, stream>>>(ei, row_st, sorted, cebuf, P, QA);
    k_fold<<<32, 256, 0, stream>>>(wpack, cebuf, mbu);      // c_e dead now
    k_swz2<<<192, 256, 0, stream>>>(wpack, cebuf);
    k_upd2<<<ROWS/64, 256, 0, stream>>>(buf1, QA, cebuf, wpack, mbu, row_st, tng, d_out);
  } else {
    k_gather<<<ROWS/4, 256, 0, stream>>>(ei, row_st, sorted, cebuf, wpack, buf1, P, aggrb);
    k_swz_upd<<<176, 256, 0, stream>>>(wpack, cebuf);
    k_upd<<<ROWS/64, 256, 0, stream>>>(buf1, aggrb, cebuf, wpack, tng, d_out);
  }
}